// Round 13
// baseline (162.300 us; speedup 1.0000x reference)
//
#include <hip/hip_runtime.h>
#include <math.h>

typedef __attribute__((ext_vector_type(8))) short short8;
typedef __attribute__((ext_vector_type(4))) float f32x4;

#define NB 4
#define NH 16
#define SL 1024
#define DH 64
#define BQ 64      // q rows per block (4 waves x 16)
#define WQ 16      // q rows per wave
#define KTL 32     // k rows per tile
#define NT 256
#define NKT (SL / KTL)                  // 32 tiles

#define TILE_SH (KTL * DH)              // 2048 shorts per tile (4 KB, bf16-only)
#define HEAD_SH ((size_t)NKT * TILE_SH) // 65536 shorts per head (128 KB)
#define BLOB_SH ((size_t)NB * NH * HEAD_SH)  // 8 MB per blob
#define BMROW   (SL / 32)               // 32 dwords of mask bits per q row

// 0.125 * log2(e): scores computed directly in log2 domain
#define QSCALE 0.18033688011111543f
#define NEGB  -1.5e9f                   // masked bias; exp2 underflows to exact 0

#if __has_builtin(__builtin_amdgcn_exp2f)
#define EXP2F(x) __builtin_amdgcn_exp2f(x)
#else
#define EXP2F(x) exp2f(x)
#endif

__device__ __forceinline__ unsigned short bf_rne(float x) {
    unsigned int u = __float_as_uint(x);
    u += 0x7fffu + ((u >> 16) & 1u);
    return (unsigned short)(u >> 16);
}
__device__ __forceinline__ void bf_split(float x, unsigned short& h, unsigned short& l) {
    unsigned int u = __float_as_uint(x);
    h = (unsigned short)(u >> 16);                       // truncate
    float r = x - __uint_as_float(u & 0xffff0000u);      // exact residual
    l = bf_rne(r);
}

typedef const __attribute__((address_space(1))) unsigned int guint_t;
typedef __attribute__((address_space(3))) unsigned int luint_t;
__device__ __forceinline__ void gload_lds16(const void* g, void* l) {
    __builtin_amdgcn_global_load_lds((guint_t*)g, (luint_t*)l, 16, 0, 0);
}

#define MFMA(a, b, c) __builtin_amdgcn_mfma_f32_16x16x32_bf16(a, b, c, 0, 0, 0)

#define WAITVM(N) do { asm volatile("s_waitcnt vmcnt(" #N ")" ::: "memory"); \
                       __builtin_amdgcn_sched_barrier(0); } while (0)
#define BAR() do { __builtin_amdgcn_sched_barrier(0); __builtin_amdgcn_s_barrier(); \
                   __builtin_amdgcn_sched_barrier(0); } while (0)
#define SCHED_FENCE() __builtin_amdgcn_sched_barrier(0)

// ============================================================================
// prep_mask: pack int mask [B,1,L,L] -> bitmask [B][L][L/32] via ballot
// ============================================================================
__global__ __launch_bounds__(NT, 4) void prep_mask(
    const int* __restrict__ M, unsigned* __restrict__ bm)
{
    const size_t total = (size_t)NB * SL * SL;
    const int l = threadIdx.x & 63;
    for (size_t i = (size_t)blockIdx.x * NT + threadIdx.x; i < total;
         i += (size_t)gridDim.x * NT) {
        int v = M[i];
        unsigned long long b = __ballot(v != 0);
        if (l == 0)       bm[i >> 5] = (unsigned)b;
        else if (l == 32) bm[i >> 5] = (unsigned)(b >> 32);
    }
}

// ============================================================================
// prep_split: pure-bf16 (RNE) blobs, LDS-linear swizzled:
//   K tile: [kr][d ^ ((kr&7)<<3)]   (row = 64 shorts)
//   V tile: [d][k ^ ((d&3)<<3)]     (row = 32 shorts)
// ============================================================================
__global__ __launch_bounds__(NT, 4) void prep_split(
    const float* __restrict__ K, const float* __restrict__ V,
    unsigned short* __restrict__ kb, unsigned short* __restrict__ vb)
{
    __shared__ float sVs[KTL][DH + 4];

    const int t = threadIdx.x;
    const int kt = blockIdx.x, h = blockIdx.y, b = blockIdx.z;
    const size_t goff = (size_t)(b * NH + h) * SL * DH + (size_t)kt * KTL * DH;
    const size_t tks = (size_t)(b * NH + h) * HEAD_SH + (size_t)kt * TILE_SH;

    {
        int kr = t >> 3, c8 = t & 7;
        const float* src = K + goff + kr * DH + c8 * 8;
        float4 a = *(const float4*)src;
        float4 bb = *(const float4*)(src + 4);
        float vals[8] = {a.x, a.y, a.z, a.w, bb.x, bb.y, bb.z, bb.w};
        unsigned int pk[4];
        #pragma unroll
        for (int j = 0; j < 4; ++j)
            pk[j] = (unsigned int)bf_rne(vals[2 * j]) |
                    ((unsigned int)bf_rne(vals[2 * j + 1]) << 16);
        int dsw = (c8 * 8) ^ ((kr & 7) << 3);
        *(uint4*)&kb[tks + kr * DH + dsw] = make_uint4(pk[0], pk[1], pk[2], pk[3]);
    }

    #pragma unroll
    for (int u = 0; u < 2; ++u) {
        int i = u * NT + t;
        float4 v = *(const float4*)(V + goff + (size_t)i * 4);
        *(float4*)&sVs[i >> 4][(i & 15) * 4] = v;
    }
    __syncthreads();
    {
        int d = t >> 2, k8 = t & 3;
        float vals[8];
        #pragma unroll
        for (int j = 0; j < 8; ++j) vals[j] = sVs[k8 * 8 + j][d];
        unsigned int pk[4];
        #pragma unroll
        for (int j = 0; j < 4; ++j)
            pk[j] = (unsigned int)bf_rne(vals[2 * j]) |
                    ((unsigned int)bf_rne(vals[2 * j + 1]) << 16);
        int ksw = (k8 * 8) ^ ((d & 3) << 3);
        *(uint4*)&vb[tks + d * KTL + ksw] = make_uint4(pk[0], pk[1], pk[2], pk[3]);
    }
}

// ============================================================================
// Main: two-pass softmax attention, pure-bf16 MFMA, depth-3 DMA pipeline,
// FIXED-REFERENCE softmax: pass 1 has ZERO cross-lane ops (scores bounded in
// log2 domain, fp32 sums exp2(s) directly; one shuffle-reduce after the loop).
// ============================================================================
__global__ __launch_bounds__(NT, 4) void attn_main(
    const float* __restrict__ Q, const unsigned* __restrict__ bm,
    const unsigned short* __restrict__ kb, const unsigned short* __restrict__ vb,
    float* __restrict__ O, float* __restrict__ P)
{
    __shared__ unsigned short sK[4][TILE_SH];   // 16384 B
    __shared__ unsigned short sV[4][TILE_SH];   // 16384 B
    __shared__ unsigned short sPh[4][WQ][KTL];  // 4096 B

    const int t = threadIdx.x;
    const int l = t & 63;
    const int w = __builtin_amdgcn_readfirstlane(t >> 6);
    const int lg = l >> 4, lr = l & 15;

    const int flat = blockIdx.x + (blockIdx.y << 4) + (blockIdx.z << 8);
    const int nid = (flat & 7) * 128 + (flat >> 3);
    const int qt = nid & 15;
    const int hh_ = (nid >> 4) & 15;
    const int b = nid >> 8;
    const int qb = qt * BQ + w * WQ;

    const size_t hoff = (size_t)(b * NH + hh_) * SL * DH;
    const size_t headsh = (size_t)(b * NH + hh_) * HEAD_SH;
    const unsigned short* kbh = kb + headsh;
    const unsigned short* vbh = vb + headsh;
    const unsigned* bmRow = bm + ((size_t)b * SL + qb + lr) * BMROW;
    float* Pw = P + ((size_t)(b * NH + hh_) * SL + qb) * SL;
    float* Ow = O + hoff + (size_t)qb * DH;

    short8 qf[2];
    {
        const float* src0 = Q + hoff + (size_t)(qb + lr) * DH + lg * 8;
        #pragma unroll
        for (int ds = 0; ds < 2; ++ds) {
            const float* src = src0 + ds * 32;
            float4 a = *(const float4*)src;
            float4 bb = *(const float4*)(src + 4);
            float vals[8] = {a.x, a.y, a.z, a.w, bb.x, bb.y, bb.z, bb.w};
            #pragma unroll
            for (int j = 0; j < 8; ++j)
                qf[ds][j] = (short)bf_rne(vals[j] * QSCALE);
        }
    }

    auto stage = [&](unsigned short* lds, const unsigned short* gtile) {
        gload_lds16((const char*)gtile + w * 1024 + l * 16, (char*)lds + w * 1024);
    };

    const f32x4 zero = {0.f, 0.f, 0.f, 0.f};
    float psum0 = 0.f, psum1 = 0.f;      // per-lane partial sums (2 chains)
    unsigned bm0, bm1, bm2, bm3 = 0;

// ---- pass 1 step: consume tile KT from buf BUF; prefetch KT+3; lane-local sum
#define P1_STEP(BUF, KT, BMC, BMN) do {                                        \
    WAITVM(4); BAR();                                                          \
    stage(sK[((BUF) + 3) & 3], kbh + (size_t)(((KT) + 3) & 31) * TILE_SH);     \
    BMN = bmRow[((KT) + 3) & 31];                                              \
    SCHED_FENCE();                                                             \
    f32x4 acc[2];                                                              \
    _Pragma("unroll")                                                          \
    for (int st = 0; st < 2; ++st) {                                           \
        const int krow = st * 16 + lr;                                         \
        const int sw = (krow & 7) << 3;                                        \
        short8 a0 = *(const short8*)&sK[BUF][krow * DH + ((lg * 8) ^ sw)];     \
        short8 a1 = *(const short8*)&sK[BUF][krow * DH + ((32 + lg * 8) ^ sw)];\
        f32x4 c = MFMA(a0, qf[0], zero);                                       \
        acc[st] = MFMA(a1, qf[1], c);                                          \
    }                                                                          \
    float t0 = 0.f, t1 = 0.f;                                                  \
    _Pragma("unroll")                                                          \
    for (int j = 0; j < 4; ++j) {                                              \
        unsigned b0_ = ((BMC) >> (lg * 4 + j)) & 1u;                           \
        unsigned b1_ = ((BMC) >> (16 + lg * 4 + j)) & 1u;                      \
        t0 += EXP2F(acc[0][j] + (b0_ ? 0.f : NEGB));                           \
        t1 += EXP2F(acc[1][j] + (b1_ ? 0.f : NEGB));                           \
    }                                                                          \
    psum0 += t0;                                                               \
    psum1 += t1;                                                               \
} while (0)

    // pass-1 prologue: depth-3 prefetch
    stage(sK[0], kbh);                       bm0 = bmRow[0];
    stage(sK[1], kbh + TILE_SH);             bm1 = bmRow[1];
    stage(sK[2], kbh + 2 * (size_t)TILE_SH); bm2 = bmRow[2];

    for (int g = 0; g < NKT; g += 4) {
        P1_STEP(0, g + 0, bm0, bm3);
        P1_STEP(1, g + 1, bm1, bm0);
        P1_STEP(2, g + 2, bm2, bm1);
        P1_STEP(3, g + 3, bm3, bm2);
    }

    WAITVM(0); BAR();                        // drain wrap stages; sync waves

    // one-time reduce across the 4 lanes sharing q-row lr
    float sum = psum0 + psum1;
    sum += __shfl_xor(sum, 16);
    sum += __shfl_xor(sum, 32);
    sum = fmaxf(sum, 1e-35f);                // guard (fully-masked row)
    const float m2 = __log2f(sum);           // p = exp2(s - m2)

    // ================= Pass 2 =================
    f32x4 oacc[4];
    #pragma unroll
    for (int mt = 0; mt < 4; ++mt) oacc[mt] = zero;

// ---- pass 2 step: triple-prefetch (K,V,bm); QK -> p -> P store -> PV
#define P2_STEP(BUF, KT, WN, BMC, BMN) do {                                    \
    WAITVM(WN); BAR();                                                         \
    stage(sK[((BUF) + 3) & 3], kbh + (size_t)(((KT) + 3) & 31) * TILE_SH);     \
    stage(sV[((BUF) + 3) & 3], vbh + (size_t)(((KT) + 3) & 31) * TILE_SH);     \
    BMN = bmRow[((KT) + 3) & 31];                                              \
    SCHED_FENCE();                                                             \
    const int k0 = (KT) * KTL;                                                 \
    f32x4 acc[2];                                                              \
    _Pragma("unroll")                                                          \
    for (int st = 0; st < 2; ++st) {                                           \
        const int krow = st * 16 + lr;                                         \
        const int sw = (krow & 7) << 3;                                        \
        short8 a0 = *(const short8*)&sK[BUF][krow * DH + ((lg * 8) ^ sw)];     \
        short8 a1 = *(const short8*)&sK[BUF][krow * DH + ((32 + lg * 8) ^ sw)];\
        f32x4 c = MFMA(a0, qf[0], zero);                                       \
        acc[st] = MFMA(a1, qf[1], c);                                          \
    }                                                                          \
    _Pragma("unroll")                                                          \
    for (int st = 0; st < 2; ++st) {                                           \
        float p[4];                                                            \
        _Pragma("unroll")                                                      \
        for (int j = 0; j < 4; ++j) {                                          \
            unsigned bit = ((BMC) >> (st * 16 + lg * 4 + j)) & 1u;             \
            float sj = acc[st][j] + (bit ? 0.f : NEGB);                        \
            p[j] = EXP2F(sj - m2);                                             \
        }                                                                      \
        f32x4 pv4 = {p[0], p[1], p[2], p[3]};                                  \
        __builtin_nontemporal_store(                                           \
            pv4, (f32x4*)(Pw + (size_t)lr * SL + (k0 + st * 16 + lg * 4)));    \
        int col = (st * 16 + lg * 4) ^ ((lr & 3) << 3);                        \
        uint2 uh;                                                              \
        uh.x = (unsigned int)bf_rne(p[0]) | ((unsigned int)bf_rne(p[1]) << 16);\
        uh.y = (unsigned int)bf_rne(p[2]) | ((unsigned int)bf_rne(p[3]) << 16);\
        *(uint2*)&sPh[w][lr][col] = uh;                                        \
    }                                                                          \
    const int pcol = (lg * 8) ^ ((lr & 3) << 3);                               \
    short8 pb = *(const short8*)&sPh[w][lr][pcol];                             \
    _Pragma("unroll")                                                          \
    for (int mt = 0; mt < 4; ++mt) {                                           \
        const int d = mt * 16 + lr;                                            \
        const int col = (lg * 8) ^ ((d & 3) << 3);                             \
        short8 vf = *(const short8*)&sV[BUF][d * KTL + col];                   \
        oacc[mt] = MFMA(vf, pb, oacc[mt]);                                     \
    }                                                                          \
} while (0)

    // pass-2 prologue: triples (K, V, bm) for tiles 0..2
    stage(sK[0], kbh);                       stage(sV[0], vbh);                       bm0 = bmRow[0];
    stage(sK[1], kbh + TILE_SH);             stage(sV[1], vbh + TILE_SH);             bm1 = bmRow[1];
    stage(sK[2], kbh + 2 * (size_t)TILE_SH); stage(sV[2], vbh + 2 * (size_t)TILE_SH); bm2 = bmRow[2];

    // peeled first group: exact vmcnt counts, then steady 12
    P2_STEP(0, 0, 6, bm0, bm3);
    P2_STEP(1, 1, 8, bm1, bm0);
    P2_STEP(2, 2, 10, bm2, bm1);
    P2_STEP(3, 3, 12, bm3, bm2);
    for (int g = 4; g < NKT; g += 4) {
        P2_STEP(0, g + 0, 12, bm0, bm3);
        P2_STEP(1, g + 1, 12, bm1, bm0);
        P2_STEP(2, g + 2, 12, bm2, bm1);
        P2_STEP(3, g + 3, 12, bm3, bm2);
    }

    WAITVM(0);                               // drain wrap stages before endpgm
    #pragma unroll
    for (int mt = 0; mt < 4; ++mt) {
        __builtin_nontemporal_store(
            oacc[mt], (f32x4*)(Ow + (size_t)lr * DH + mt * 16 + lg * 4));
    }
#undef P1_STEP
#undef P2_STEP
}

// ============================================================================
// Fallback (verified round-2 kernel, full split precision) if ws too small
// ============================================================================
__global__ __launch_bounds__(NT, 2) void attn_fallback(
    const float* __restrict__ Q, const float* __restrict__ K,
    const float* __restrict__ V, const int* __restrict__ M,
    float* __restrict__ O, float* __restrict__ P)
{
    __shared__ unsigned short sKhi[64][DH];
    __shared__ unsigned short sKlo[64][DH];
    __shared__ unsigned short sVhi[DH][64];
    __shared__ unsigned short sVlo[DH][64];
    __shared__ unsigned short sPhi[4][WQ][64];
    __shared__ unsigned short sPlo[4][WQ][64];

    const int t = threadIdx.x;
    const int l = t & 63;
    const int w = t >> 6;
    const int lg = l >> 4;
    const int lr = l & 15;

    const int hh_ = blockIdx.y, b = blockIdx.z;
    const int qb = blockIdx.x * BQ + w * WQ;

    const size_t hoff = (size_t)(b * NH + hh_) * SL * DH;
    const float* Kh = K + hoff;
    const float* Vh = V + hoff;
    const int*   Mw = M + ((size_t)b * SL + qb) * SL;
    float*       Pw = P + ((size_t)(b * NH + hh_) * SL + qb) * SL;
    float*       Ow = O + hoff + (size_t)qb * DH;

    short8 qhi[2], qlo[2];
    {
        const float* src0 = Q + hoff + (size_t)(qb + lr) * DH + lg * 8;
        #pragma unroll
        for (int ds = 0; ds < 2; ++ds) {
            const float* src = src0 + ds * 32;
            float4 a = *(const float4*)src;
            float4 bb = *(const float4*)(src + 4);
            float vals[8] = {a.x, a.y, a.z, a.w, bb.x, bb.y, bb.z, bb.w};
            #pragma unroll
            for (int j = 0; j < 8; ++j) {
                unsigned short hv, lv;
                bf_split(vals[j] * 0.125f, hv, lv);
                qhi[ds][j] = (short)hv;
                qlo[ds][j] = (short)lv;
            }
        }
    }

    auto stageK = [&](int k0) {
        #pragma unroll
        for (int u = 0; u < 2; ++u) {
            int idx = u * NT + t;
            int kr = idx >> 3;
            int dc = (idx & 7) * 8;
            const float* src = Kh + (size_t)(k0 + kr) * DH + dc;
            float4 a = *(const float4*)src;
            float4 bb = *(const float4*)(src + 4);
            float vals[8] = {a.x, a.y, a.z, a.w, bb.x, bb.y, bb.z, bb.w};
            unsigned int ph[4], pl[4];
            #pragma unroll
            for (int j = 0; j < 4; ++j) {
                unsigned short h0, l0, h1, l1;
                bf_split(vals[2 * j], h0, l0);
                bf_split(vals[2 * j + 1], h1, l1);
                ph[j] = (unsigned int)h0 | ((unsigned int)h1 << 16);
                pl[j] = (unsigned int)l0 | ((unsigned int)l1 << 16);
            }
            int dsw = dc ^ ((kr & 7) << 3);
            *(uint4*)&sKhi[kr][dsw] = make_uint4(ph[0], ph[1], ph[2], ph[3]);
            *(uint4*)&sKlo[kr][dsw] = make_uint4(pl[0], pl[1], pl[2], pl[3]);
        }
    };

    float m = -INFINITY, sum = 0.f;
    for (int kt = 0; kt < 16; ++kt) {
        const int k0 = kt * 64;
        __syncthreads();
        stageK(k0);
        __syncthreads();
        f32x4 acc[4];
        #pragma unroll
        for (int st = 0; st < 4; ++st) {
            const int krow = st * 16 + lr;
            const int sw = (krow & 7) << 3;
            f32x4 c = {0.f, 0.f, 0.f, 0.f};
            #pragma unroll
            for (int ds = 0; ds < 2; ++ds) {
                int dc = (ds * 32 + lg * 8) ^ sw;
                short8 ah = *(const short8*)&sKhi[krow][dc];
                short8 al = *(const short8*)&sKlo[krow][dc];
                c = MFMA(ah, qhi[ds], c);
                c = MFMA(ah, qlo[ds], c);
                c = MFMA(al, qhi[ds], c);
            }
            acc[st] = c;
        }
        float s[16];
        #pragma unroll
        for (int st = 0; st < 4; ++st) {
            const int4 mv = *(const int4*)(Mw + (size_t)lr * SL + k0 + st * 16 + lg * 4);
            s[st * 4 + 0] = mv.x ? acc[st][0] : -1e9f;
            s[st * 4 + 1] = mv.y ? acc[st][1] : -1e9f;
            s[st * 4 + 2] = mv.z ? acc[st][2] : -1e9f;
            s[st * 4 + 3] = mv.w ? acc[st][3] : -1e9f;
        }
        float tmax = s[0];
        #pragma unroll
        for (int j = 1; j < 16; ++j) tmax = fmaxf(tmax, s[j]);
        tmax = fmaxf(tmax, __shfl_xor(tmax, 16));
        tmax = fmaxf(tmax, __shfl_xor(tmax, 32));
        const float mn = fmaxf(m, tmax);
        float ts = 0.f;
        #pragma unroll
        for (int j = 0; j < 16; ++j) ts += __expf(s[j] - mn);
        ts += __shfl_xor(ts, 16);
        ts += __shfl_xor(ts, 32);
        sum = sum * __expf(m - mn) + ts;
        m = mn;
    }
    const float inv = 1.f / sum;

    f32x4 oacc[4];
    #pragma unroll
    for (int mt = 0; mt < 4; ++mt) oacc[mt] = (f32x4){0.f, 0.f, 0.f, 0.f};

    for (int kt = 0; kt < 16; ++kt) {
        const int k0 = kt * 64;
        __syncthreads();
        stageK(k0);
        {
            int d0 = (t & 15) * 4;
            int kl0 = (t >> 4) * 4;
            float4 r[4];
            #pragma unroll
            for (int i = 0; i < 4; ++i)
                r[i] = *(const float4*)(Vh + (size_t)(k0 + kl0 + i) * DH + d0);
            const float* rp = (const float*)r;
            #pragma unroll
            for (int j = 0; j < 4; ++j) {
                unsigned short hv[4], lv[4];
                #pragma unroll
                for (int i = 0; i < 4; ++i) bf_split(rp[i * 4 + j], hv[i], lv[i]);
                int d = d0 + j;
                int csw = kl0 ^ ((d & 7) << 3);
                uint2 uh, ul;
                uh.x = (unsigned int)hv[0] | ((unsigned int)hv[1] << 16);
                uh.y = (unsigned int)hv[2] | ((unsigned int)hv[3] << 16);
                ul.x = (unsigned int)lv[0] | ((unsigned int)lv[1] << 16);
                ul.y = (unsigned int)lv[2] | ((unsigned int)lv[3] << 16);
                *(uint2*)&sVhi[d][csw] = uh;
                *(uint2*)&sVlo[d][csw] = ul;
            }
        }
        __syncthreads();

        #pragma unroll
        for (int st = 0; st < 4; ++st) {
            const int krow = st * 16 + lr;
            const int sw = (krow & 7) << 3;
            f32x4 c = {0.f, 0.f, 0.f, 0.f};
            #pragma unroll
            for (int ds = 0; ds < 2; ++ds) {
                int dc = (ds * 32 + lg * 8) ^ sw;
                short8 ah = *(const short8*)&sKhi[krow][dc];
                short8 al = *(const short8*)&sKlo[krow][dc];
                c = MFMA(ah, qhi[ds], c);
                c = MFMA(ah, qlo[ds], c);
                c = MFMA(al, qhi[ds], c);
            }
            const int4 mv = *(const int4*)(Mw + (size_t)lr * SL + k0 + st * 16 + lg * 4);
            float p0 = mv.x ? __expf(c[0] - m) * inv : 0.f;
            float p1 = mv.y ? __expf(c[1] - m) * inv : 0.f;
            float p2 = mv.z ? __expf(c[2] - m) * inv : 0.f;
            float p3 = mv.w ? __expf(c[3] - m) * inv : 0.f;
            *(float4*)(Pw + (size_t)lr * SL + (k0 + st * 16 + lg * 4)) =
                make_float4(p0, p1, p2, p3);
            unsigned short hv[4], lv[4];
            bf_split(p0, hv[0], lv[0]);
            bf_split(p1, hv[1], lv[1]);
            bf_split(p2, hv[2], lv[2]);
            bf_split(p3, hv[3], lv[3]);
            int col = (st * 16 + lg * 4) ^ ((lr & 7) << 3);
            uint2 uh, ul;
            uh.x = (unsigned int)hv[0] | ((unsigned int)hv[1] << 16);
            uh.y = (unsigned int)hv[2] | ((unsigned int)hv[3] << 16);
            ul.x = (unsigned int)lv[0] | ((unsigned int)lv[1] << 16);
            ul.y = (unsigned int)lv[2] | ((unsigned int)lv[3] << 16);
            *(uint2*)&sPhi[w][lr][col] = uh;
            *(uint2*)&sPlo[w][lr][col] = ul;
        }

        short8 pbh[2], pbl[2];
        #pragma unroll
        for (int ks = 0; ks < 2; ++ks) {
            int col = (ks * 32 + lg * 8) ^ ((lr & 7) << 3);
            pbh[ks] = *(const short8*)&sPhi[w][lr][col];
            pbl[ks] = *(const short8*)&sPlo[w][lr][col];
        }
        #pragma unroll
        for (int mt = 0; mt < 4; ++mt) {
            const int d = mt * 16 + lr;
            const int swd = (d & 7) << 3;
            #pragma unroll
            for (int ks = 0; ks < 2; ++ks) {
                int col = (ks * 32 + lg * 8) ^ swd;
                short8 vh = *(const short8*)&sVhi[d][col];
                short8 vl = *(const short8*)&sVlo[d][col];
                oacc[mt] = MFMA(vh, pbh[ks], oacc[mt]);
                oacc[mt] = MFMA(vh, pbl[ks], oacc[mt]);
                oacc[mt] = MFMA(vl, pbh[ks], oacc[mt]);
            }
        }
    }

    #pragma unroll
    for (int mt = 0; mt < 4; ++mt) {
        float4 o = make_float4(oacc[mt][0], oacc[mt][1], oacc[mt][2], oacc[mt][3]);
        *(float4*)(Ow + (size_t)lr * DH + mt * 16 + lg * 4) = o;
    }
}

extern "C" void kernel_launch(void* const* d_in, const int* in_sizes, int n_in,
                              void* d_out, int out_size, void* d_ws, size_t ws_size,
                              hipStream_t stream) {
    const float* Q = (const float*)d_in[0];
    const float* K = (const float*)d_in[1];
    const float* V = (const float*)d_in[2];
    const int*   M = (const int*)d_in[3];
    float* O = (float*)d_out;
    float* P = O + (size_t)NB * NH * SL * DH;   // outputs: out, p_attn

    const size_t bm_dw = (size_t)NB * SL * BMROW;          // 512 KB
    const size_t need = bm_dw * 4 + 2 * BLOB_SH * 2;       // 512KB + 16MB
    if (ws_size >= need) {
        unsigned* bmp = (unsigned*)d_ws;
        unsigned short* kbp = (unsigned short*)(bmp + bm_dw);
        unsigned short* vbp = kbp + BLOB_SH;
        hipLaunchKernelGGL(prep_mask, dim3(1024, 1, 1), dim3(NT, 1, 1), 0, stream, M, bmp);
        hipLaunchKernelGGL(prep_split, dim3(NKT, NH, NB), dim3(NT, 1, 1), 0, stream,
                           K, V, kbp, vbp);
        hipLaunchKernelGGL(attn_main, dim3(SL / BQ, NH, NB), dim3(NT, 1, 1), 0, stream,
                           Q, bmp, kbp, vbp, O, P);
    } else {
        hipLaunchKernelGGL(attn_fallback, dim3(SL / BQ, NH, NB), dim3(NT, 1, 1), 0, stream,
                           Q, K, V, M, O, P);
    }
}

// Round 14
// 155.797 us; speedup vs baseline: 1.0417x; 1.0417x over previous
//
#include <hip/hip_runtime.h>
#include <math.h>

typedef __attribute__((ext_vector_type(8))) short short8;
typedef __attribute__((ext_vector_type(4))) float f32x4;

#define NB 4
#define NH 16
#define SL 1024
#define DH 64
#define BQ 64      // q rows per block (4 waves x 16)
#define WQ 16      // q rows per wave
#define KTL 64     // k rows per tile (steps halved vs r13)
#define NT 256
#define NKT (SL / KTL)                  // 16 tiles

#define TILE_SH (KTL * DH)              // 4096 shorts per tile (8 KB)
#define TILE_B  (TILE_SH * 2)           // 8192 bytes
#define HEAD_SH ((size_t)NKT * TILE_SH) // 65536 shorts per head
#define BLOB_SH ((size_t)NB * NH * HEAD_SH)  // 8 MB per blob
#define BMROW   (SL / 32)               // 32 dwords of mask bits per q row

#define QSCALE 0.18033688011111543f     // 0.125 * log2(e)
#define NEGB  -1.5e9f                   // masked bias; exp2 underflows to exact 0

#if __has_builtin(__builtin_amdgcn_exp2f)
#define EXP2F(x) __builtin_amdgcn_exp2f(x)
#else
#define EXP2F(x) exp2f(x)
#endif

__device__ __forceinline__ unsigned short bf_rne(float x) {
    unsigned int u = __float_as_uint(x);
    u += 0x7fffu + ((u >> 16) & 1u);
    return (unsigned short)(u >> 16);
}
__device__ __forceinline__ void bf_split(float x, unsigned short& h, unsigned short& l) {
    unsigned int u = __float_as_uint(x);
    h = (unsigned short)(u >> 16);
    float r = x - __uint_as_float(u & 0xffff0000u);
    l = bf_rne(r);
}

typedef const __attribute__((address_space(1))) unsigned int guint_t;
typedef __attribute__((address_space(3))) unsigned int luint_t;
__device__ __forceinline__ void gload_lds16(const void* g, void* l) {
    __builtin_amdgcn_global_load_lds((guint_t*)g, (luint_t*)l, 16, 0, 0);
}

#define MFMA(a, b, c) __builtin_amdgcn_mfma_f32_16x16x32_bf16(a, b, c, 0, 0, 0)

#define WAITVM(N) do { asm volatile("s_waitcnt vmcnt(" #N ")" ::: "memory"); \
                       __builtin_amdgcn_sched_barrier(0); } while (0)
#define BAR() do { __builtin_amdgcn_sched_barrier(0); __builtin_amdgcn_s_barrier(); \
                   __builtin_amdgcn_sched_barrier(0); } while (0)
#define SCHED_FENCE() __builtin_amdgcn_sched_barrier(0)

// ============================================================================
// prep_mask: pack int mask [B,1,L,L] -> bitmask [B][L][L/32] via ballot
// ============================================================================
__global__ __launch_bounds__(NT, 4) void prep_mask(
    const int* __restrict__ M, unsigned* __restrict__ bm)
{
    const size_t total = (size_t)NB * SL * SL;
    const int l = threadIdx.x & 63;
    for (size_t i = (size_t)blockIdx.x * NT + threadIdx.x; i < total;
         i += (size_t)gridDim.x * NT) {
        int v = M[i];
        unsigned long long b = __ballot(v != 0);
        if (l == 0)       bm[i >> 5] = (unsigned)b;
        else if (l == 32) bm[i >> 5] = (unsigned)(b >> 32);
    }
}

// ============================================================================
// prep_split: pure-bf16 (RNE) blobs, LDS-linear swizzled (KTL=64):
//   K tile: [kr 0..63][d ^ ((kr&7)<<3)]   (row = 64 shorts)
//   V tile: [d 0..63][k ^ ((d&7)<<3)]     (row = 64 shorts)
// ============================================================================
__global__ __launch_bounds__(NT, 2) void prep_split(
    const float* __restrict__ K, const float* __restrict__ V,
    unsigned short* __restrict__ kb, unsigned short* __restrict__ vb)
{
    __shared__ float sVs[KTL][DH + 4];

    const int t = threadIdx.x;
    const int kt = blockIdx.x, h = blockIdx.y, b = blockIdx.z;
    const size_t goff = (size_t)(b * NH + h) * SL * DH + (size_t)kt * KTL * DH;
    const size_t tks = (size_t)(b * NH + h) * HEAD_SH + (size_t)kt * TILE_SH;

    // ---- K: 64 rows x 8 chunks = 512 granules, 2/thread
    #pragma unroll
    for (int u = 0; u < 2; ++u) {
        int idx = u * NT + t;
        int kr = idx >> 3, c8 = idx & 7;
        const float* src = K + goff + kr * DH + c8 * 8;
        float4 a = *(const float4*)src;
        float4 bb = *(const float4*)(src + 4);
        float vals[8] = {a.x, a.y, a.z, a.w, bb.x, bb.y, bb.z, bb.w};
        unsigned int pk[4];
        #pragma unroll
        for (int j = 0; j < 4; ++j)
            pk[j] = (unsigned int)bf_rne(vals[2 * j]) |
                    ((unsigned int)bf_rne(vals[2 * j + 1]) << 16);
        int dsw = (c8 * 8) ^ ((kr & 7) << 3);
        *(uint4*)&kb[tks + kr * DH + dsw] = make_uint4(pk[0], pk[1], pk[2], pk[3]);
    }

    // ---- V: stage fp32 tile (64x64), transpose via LDS
    #pragma unroll
    for (int u = 0; u < 4; ++u) {
        int i = u * NT + t;                   // float4 id 0..1023
        float4 v = *(const float4*)(V + goff + (size_t)i * 4);
        *(float4*)&sVs[i >> 4][(i & 15) * 4] = v;
    }
    __syncthreads();
    #pragma unroll
    for (int u = 0; u < 2; ++u) {
        int idx = u * NT + t;                 // 64 d x 8 kchunks = 512 granules
        int d = idx & 63, k8 = idx >> 6;      // u=0: k8 0..3, u=1: 4..7
        float vals[8];
        #pragma unroll
        for (int j = 0; j < 8; ++j) vals[j] = sVs[k8 * 8 + j][d];
        unsigned int pk[4];
        #pragma unroll
        for (int j = 0; j < 4; ++j)
            pk[j] = (unsigned int)bf_rne(vals[2 * j]) |
                    ((unsigned int)bf_rne(vals[2 * j + 1]) << 16);
        int ksw = (k8 * 8) ^ ((d & 7) << 3);
        *(uint4*)&vb[tks + d * KTL + ksw] = make_uint4(pk[0], pk[1], pk[2], pk[3]);
    }
}

// ============================================================================
// Common per-block geometry
// ============================================================================
#define BLOCK_PROLOG                                                           \
    const int t = threadIdx.x;                                                 \
    const int l = t & 63;                                                      \
    const int w = __builtin_amdgcn_readfirstlane(t >> 6);                      \
    const int lg = l >> 4, lr = l & 15;                                        \
    const int flat = blockIdx.x + (blockIdx.y << 4) + (blockIdx.z << 8);       \
    const int nid = (flat & 7) * 128 + (flat >> 3);                            \
    const int qt = nid & 15;                                                   \
    const int hh_ = (nid >> 4) & 15;                                           \
    const int b = nid >> 8;                                                    \
    const int qb = qt * BQ + w * WQ;                                           \
    const size_t hoff = (size_t)(b * NH + hh_) * SL * DH;                      \
    const size_t headsh = (size_t)(b * NH + hh_) * HEAD_SH;                    \
    const size_t sbase = (size_t)(b * NH + hh_) * SL;

#define LOAD_QF                                                                \
    short8 qf[2];                                                              \
    {                                                                          \
        const float* src0 = Q + hoff + (size_t)(qb + lr) * DH + lg * 8;        \
        _Pragma("unroll")                                                      \
        for (int ds = 0; ds < 2; ++ds) {                                       \
            const float* src = src0 + ds * 32;                                 \
            float4 a = *(const float4*)src;                                    \
            float4 bb = *(const float4*)(src + 4);                             \
            float vals[8] = {a.x, a.y, a.z, a.w, bb.x, bb.y, bb.z, bb.w};      \
            _Pragma("unroll")                                                  \
            for (int j = 0; j < 8; ++j)                                        \
                qf[ds][j] = (short)bf_rne(vals[j] * QSCALE);                   \
        }                                                                      \
    }

// QK^T over a KTL=64 tile: 4 sub-tiles x 2 MFMA
#define QK_TILE(SBUF, ACC)                                                     \
    _Pragma("unroll")                                                          \
    for (int st = 0; st < 4; ++st) {                                           \
        const int krow = st * 16 + lr;                                         \
        const int sw = (krow & 7) << 3;                                        \
        short8 a0 = *(const short8*)&(SBUF)[krow * DH + ((lg * 8) ^ sw)];      \
        short8 a1 = *(const short8*)&(SBUF)[krow * DH + ((32 + lg * 8) ^ sw)]; \
        f32x4 c = MFMA(a0, qf[0], zero);                                       \
        (ACC)[st] = MFMA(a1, qf[1], c);                                        \
    }

// ============================================================================
// Pass 1: row sums of exp2(score) (fixed-reference softmax), KTL=64
// ============================================================================
__global__ __launch_bounds__(NT, 4) void attn_p1(
    const float* __restrict__ Q, const unsigned* __restrict__ bm,
    const unsigned short* __restrict__ kb, float* __restrict__ sums)
{
    __shared__ unsigned short sK[2][TILE_SH];   // 16 KB

    BLOCK_PROLOG
    const unsigned short* kbh = kb + headsh;
    const unsigned* bmRow = bm + ((size_t)b * SL + qb + lr) * BMROW;
    LOAD_QF

    auto stage = [&](unsigned short* lds, const unsigned short* gt) {
        #pragma unroll
        for (int u = 0; u < 2; ++u) {
            const int c = w * 2 + u;       // 8 x 1KB chunks
            gload_lds16((const char*)gt + c * 1024 + l * 16, (char*)lds + c * 1024);
        }
    };

    const f32x4 zero = {0.f, 0.f, 0.f, 0.f};
    float psum = 0.f;
    uint2 bmv, bmn;
    int cur = 0;

    stage(sK[0], kbh);
    bmv = *(const uint2*)&bmRow[0];

    for (int kt = 0; kt < NKT; ++kt) {
        WAITVM(0);
        BAR();
        if (kt + 1 < NKT) {
            stage(sK[cur ^ 1], kbh + (size_t)(kt + 1) * TILE_SH);
            bmn = *(const uint2*)&bmRow[2 * (kt + 1)];
        }
        SCHED_FENCE();

        f32x4 acc[4];
        QK_TILE(sK[cur], acc);

        float ts = 0.f;
        #pragma unroll
        for (int st = 0; st < 4; ++st) {
            const unsigned bmd = (st & 2) ? bmv.y : bmv.x;
            #pragma unroll
            for (int j = 0; j < 4; ++j) {
                unsigned bit = (bmd >> ((st & 1) * 16 + lg * 4 + j)) & 1u;
                ts += EXP2F(acc[st][j] + (bit ? 0.f : NEGB));
            }
        }
        psum += ts;
        bmv = bmn;
        cur ^= 1;
    }

    float sum = psum;
    sum += __shfl_xor(sum, 16);
    sum += __shfl_xor(sum, 32);
    sum = fmaxf(sum, 1e-35f);
    if (l < 16) sums[sbase + qb + lr] = sum;
}

// ============================================================================
// Pass 2: P materialization + PV, KTL=64, store-slack vmcnt. LDS 40KB.
// ============================================================================
__global__ __launch_bounds__(NT, 4) void attn_p2(
    const float* __restrict__ Q, const unsigned* __restrict__ bm,
    const unsigned short* __restrict__ kb, const unsigned short* __restrict__ vb,
    const float* __restrict__ sums, float* __restrict__ O, float* __restrict__ P)
{
    __shared__ unsigned short sK[2][TILE_SH];   // 16 KB
    __shared__ unsigned short sV[2][TILE_SH];   // 16 KB
    __shared__ unsigned short sPh[4][WQ][KTL];  // 8 KB

    BLOCK_PROLOG
    const unsigned short* kbh = kb + headsh;
    const unsigned short* vbh = vb + headsh;
    const unsigned* bmRow = bm + ((size_t)b * SL + qb + lr) * BMROW;
    float* Pw = P + (sbase + qb) * SL;
    float* Ow = O + hoff + (size_t)qb * DH;
    LOAD_QF

    const float m2 = __log2f(sums[sbase + qb + lr]);

    auto stage = [&](unsigned short* lds, const unsigned short* gt) {
        #pragma unroll
        for (int u = 0; u < 2; ++u) {
            const int c = w * 2 + u;
            gload_lds16((const char*)gt + c * 1024 + l * 16, (char*)lds + c * 1024);
        }
    };

    const f32x4 zero = {0.f, 0.f, 0.f, 0.f};
    f32x4 oacc[4];
    #pragma unroll
    for (int mt = 0; mt < 4; ++mt) oacc[mt] = zero;
    uint2 bmv, bmn;
    int cur = 0;

    stage(sK[0], kbh);
    stage(sV[0], vbh);
    bmv = *(const uint2*)&bmRow[0];

    for (int kt = 0; kt < NKT; ++kt) {
        const int k0 = kt * KTL;
        // queue at top (kt>=1): [stores(kt-2)?] stageK/V(kt) 4 + bm(kt) 1, stores(kt-1) 4
        if (kt == 0) { WAITVM(0); } else { WAITVM(4); }
        BAR();
        if (kt + 1 < NKT) {
            stage(sK[cur ^ 1], kbh + (size_t)(kt + 1) * TILE_SH);
            stage(sV[cur ^ 1], vbh + (size_t)(kt + 1) * TILE_SH);
            bmn = *(const uint2*)&bmRow[2 * (kt + 1)];
        }
        SCHED_FENCE();

        f32x4 acc[4];
        QK_TILE(sK[cur], acc);

        #pragma unroll
        for (int st = 0; st < 4; ++st) {
            const unsigned bmd = (st & 2) ? bmv.y : bmv.x;
            float p[4];
            #pragma unroll
            for (int j = 0; j < 4; ++j) {
                unsigned bit = (bmd >> ((st & 1) * 16 + lg * 4 + j)) & 1u;
                p[j] = EXP2F(acc[st][j] + (bit ? 0.f : NEGB) - m2);
            }
            f32x4 pv4 = {p[0], p[1], p[2], p[3]};
            __builtin_nontemporal_store(
                pv4, (f32x4*)(Pw + (size_t)lr * SL + (k0 + st * 16 + lg * 4)));
            int col = (st * 16 + lg * 4) ^ ((lr & 7) << 3);
            uint2 uh;
            uh.x = (unsigned int)bf_rne(p[0]) | ((unsigned int)bf_rne(p[1]) << 16);
            uh.y = (unsigned int)bf_rne(p[2]) | ((unsigned int)bf_rne(p[3]) << 16);
            *(uint2*)&sPh[w][lr][col] = uh;
        }

        // PV: O^T += V^T * P^T  (2 k-slices x 4 d-subtiles)
        short8 pb0 = *(const short8*)&sPh[w][lr][(lg * 8) ^ ((lr & 7) << 3)];
        short8 pb1 = *(const short8*)&sPh[w][lr][(32 + lg * 8) ^ ((lr & 7) << 3)];
        #pragma unroll
        for (int mt = 0; mt < 4; ++mt) {
            const int d = mt * 16 + lr;
            const int sw = (d & 7) << 3;
            short8 v0 = *(const short8*)&sV[cur][d * KTL + ((lg * 8) ^ sw)];
            short8 v1 = *(const short8*)&sV[cur][d * KTL + ((32 + lg * 8) ^ sw)];
            oacc[mt] = MFMA(v0, pb0, oacc[mt]);
            oacc[mt] = MFMA(v1, pb1, oacc[mt]);
        }
        bmv = bmn;
        cur ^= 1;
    }

    #pragma unroll
    for (int mt = 0; mt < 4; ++mt) {
        __builtin_nontemporal_store(
            oacc[mt], (f32x4*)(Ow + (size_t)lr * DH + mt * 16 + lg * 4));
    }
}

// ============================================================================
// Fallback (verified round-2 kernel, full split precision) if ws too small
// ============================================================================
__global__ __launch_bounds__(NT, 2) void attn_fallback(
    const float* __restrict__ Q, const float* __restrict__ K,
    const float* __restrict__ V, const int* __restrict__ M,
    float* __restrict__ O, float* __restrict__ P)
{
    __shared__ unsigned short sKhi[64][DH];
    __shared__ unsigned short sKlo[64][DH];
    __shared__ unsigned short sVhi[DH][64];
    __shared__ unsigned short sVlo[DH][64];
    __shared__ unsigned short sPhi[4][WQ][64];
    __shared__ unsigned short sPlo[4][WQ][64];

    const int t = threadIdx.x;
    const int l = t & 63;
    const int w = t >> 6;
    const int lg = l >> 4;
    const int lr = l & 15;

    const int hh_ = blockIdx.y, b = blockIdx.z;
    const int qb = blockIdx.x * BQ + w * WQ;

    const size_t hoff = (size_t)(b * NH + hh_) * SL * DH;
    const float* Kh = K + hoff;
    const float* Vh = V + hoff;
    const int*   Mw = M + ((size_t)b * SL + qb) * SL;
    float*       Pw = P + ((size_t)(b * NH + hh_) * SL + qb) * SL;
    float*       Ow = O + hoff + (size_t)qb * DH;

    short8 qhi[2], qlo[2];
    {
        const float* src0 = Q + hoff + (size_t)(qb + lr) * DH + lg * 8;
        #pragma unroll
        for (int ds = 0; ds < 2; ++ds) {
            const float* src = src0 + ds * 32;
            float4 a = *(const float4*)src;
            float4 bb = *(const float4*)(src + 4);
            float vals[8] = {a.x, a.y, a.z, a.w, bb.x, bb.y, bb.z, bb.w};
            #pragma unroll
            for (int j = 0; j < 8; ++j) {
                unsigned short hv, lv;
                bf_split(vals[j] * 0.125f, hv, lv);
                qhi[ds][j] = (short)hv;
                qlo[ds][j] = (short)lv;
            }
        }
    }

    auto stageK = [&](int k0) {
        #pragma unroll
        for (int u = 0; u < 2; ++u) {
            int idx = u * NT + t;
            int kr = idx >> 3;
            int dc = (idx & 7) * 8;
            const float* src = Kh + (size_t)(k0 + kr) * DH + dc;
            float4 a = *(const float4*)src;
            float4 bb = *(const float4*)(src + 4);
            float vals[8] = {a.x, a.y, a.z, a.w, bb.x, bb.y, bb.z, bb.w};
            unsigned int ph[4], pl[4];
            #pragma unroll
            for (int j = 0; j < 4; ++j) {
                unsigned short h0, l0, h1, l1;
                bf_split(vals[2 * j], h0, l0);
                bf_split(vals[2 * j + 1], h1, l1);
                ph[j] = (unsigned int)h0 | ((unsigned int)h1 << 16);
                pl[j] = (unsigned int)l0 | ((unsigned int)l1 << 16);
            }
            int dsw = dc ^ ((kr & 7) << 3);
            *(uint4*)&sKhi[kr][dsw] = make_uint4(ph[0], ph[1], ph[2], ph[3]);
            *(uint4*)&sKlo[kr][dsw] = make_uint4(pl[0], pl[1], pl[2], pl[3]);
        }
    };

    float m = -INFINITY, sum = 0.f;
    for (int kt = 0; kt < 16; ++kt) {
        const int k0 = kt * 64;
        __syncthreads();
        stageK(k0);
        __syncthreads();
        f32x4 acc[4];
        #pragma unroll
        for (int st = 0; st < 4; ++st) {
            const int krow = st * 16 + lr;
            const int sw = (krow & 7) << 3;
            f32x4 c = {0.f, 0.f, 0.f, 0.f};
            #pragma unroll
            for (int ds = 0; ds < 2; ++ds) {
                int dc = (ds * 32 + lg * 8) ^ sw;
                short8 ah = *(const short8*)&sKhi[krow][dc];
                short8 al = *(const short8*)&sKlo[krow][dc];
                c = MFMA(ah, qhi[ds], c);
                c = MFMA(ah, qlo[ds], c);
                c = MFMA(al, qhi[ds], c);
            }
            acc[st] = c;
        }
        float s[16];
        #pragma unroll
        for (int st = 0; st < 4; ++st) {
            const int4 mv = *(const int4*)(Mw + (size_t)lr * SL + k0 + st * 16 + lg * 4);
            s[st * 4 + 0] = mv.x ? acc[st][0] : -1e9f;
            s[st * 4 + 1] = mv.y ? acc[st][1] : -1e9f;
            s[st * 4 + 2] = mv.z ? acc[st][2] : -1e9f;
            s[st * 4 + 3] = mv.w ? acc[st][3] : -1e9f;
        }
        float tmax = s[0];
        #pragma unroll
        for (int j = 1; j < 16; ++j) tmax = fmaxf(tmax, s[j]);
        tmax = fmaxf(tmax, __shfl_xor(tmax, 16));
        tmax = fmaxf(tmax, __shfl_xor(tmax, 32));
        const float mn = fmaxf(m, tmax);
        float ts = 0.f;
        #pragma unroll
        for (int j = 0; j < 16; ++j) ts += __expf(s[j] - mn);
        ts += __shfl_xor(ts, 16);
        ts += __shfl_xor(ts, 32);
        sum = sum * __expf(m - mn) + ts;
        m = mn;
    }
    const float inv = 1.f / sum;

    f32x4 oacc[4];
    #pragma unroll
    for (int mt = 0; mt < 4; ++mt) oacc[mt] = (f32x4){0.f, 0.f, 0.f, 0.f};

    for (int kt = 0; kt < 16; ++kt) {
        const int k0 = kt * 64;
        __syncthreads();
        stageK(k0);
        {
            int d0 = (t & 15) * 4;
            int kl0 = (t >> 4) * 4;
            float4 r[4];
            #pragma unroll
            for (int i = 0; i < 4; ++i)
                r[i] = *(const float4*)(Vh + (size_t)(k0 + kl0 + i) * DH + d0);
            const float* rp = (const float*)r;
            #pragma unroll
            for (int j = 0; j < 4; ++j) {
                unsigned short hv[4], lv[4];
                #pragma unroll
                for (int i = 0; i < 4; ++i) bf_split(rp[i * 4 + j], hv[i], lv[i]);
                int d = d0 + j;
                int csw = kl0 ^ ((d & 7) << 3);
                uint2 uh, ul;
                uh.x = (unsigned int)hv[0] | ((unsigned int)hv[1] << 16);
                uh.y = (unsigned int)hv[2] | ((unsigned int)hv[3] << 16);
                ul.x = (unsigned int)lv[0] | ((unsigned int)lv[1] << 16);
                ul.y = (unsigned int)lv[2] | ((unsigned int)lv[3] << 16);
                *(uint2*)&sVhi[d][csw] = uh;
                *(uint2*)&sVlo[d][csw] = ul;
            }
        }
        __syncthreads();

        #pragma unroll
        for (int st = 0; st < 4; ++st) {
            const int krow = st * 16 + lr;
            const int sw = (krow & 7) << 3;
            f32x4 c = {0.f, 0.f, 0.f, 0.f};
            #pragma unroll
            for (int ds = 0; ds < 2; ++ds) {
                int dc = (ds * 32 + lg * 8) ^ sw;
                short8 ah = *(const short8*)&sKhi[krow][dc];
                short8 al = *(const short8*)&sKlo[krow][dc];
                c = MFMA(ah, qhi[ds], c);
                c = MFMA(ah, qlo[ds], c);
                c = MFMA(al, qhi[ds], c);
            }
            const int4 mv = *(const int4*)(Mw + (size_t)lr * SL + k0 + st * 16 + lg * 4);
            float p0 = mv.x ? __expf(c[0] - m) * inv : 0.f;
            float p1 = mv.y ? __expf(c[1] - m) * inv : 0.f;
            float p2 = mv.z ? __expf(c[2] - m) * inv : 0.f;
            float p3 = mv.w ? __expf(c[3] - m) * inv : 0.f;
            *(float4*)(Pw + (size_t)lr * SL + (k0 + st * 16 + lg * 4)) =
                make_float4(p0, p1, p2, p3);
            unsigned short hv[4], lv[4];
            bf_split(p0, hv[0], lv[0]);
            bf_split(p1, hv[1], lv[1]);
            bf_split(p2, hv[2], lv[2]);
            bf_split(p3, hv[3], lv[3]);
            int col = (st * 16 + lg * 4) ^ ((lr & 7) << 3);
            uint2 uh, ul;
            uh.x = (unsigned int)hv[0] | ((unsigned int)hv[1] << 16);
            uh.y = (unsigned int)hv[2] | ((unsigned int)hv[3] << 16);
            ul.x = (unsigned int)lv[0] | ((unsigned int)lv[1] << 16);
            ul.y = (unsigned int)lv[2] | ((unsigned int)lv[3] << 16);
            *(uint2*)&sPhi[w][lr][col] = uh;
            *(uint2*)&sPlo[w][lr][col] = ul;
        }

        short8 pbh[2], pbl[2];
        #pragma unroll
        for (int ks = 0; ks < 2; ++ks) {
            int col = (ks * 32 + lg * 8) ^ ((lr & 7) << 3);
            pbh[ks] = *(const short8*)&sPhi[w][lr][col];
            pbl[ks] = *(const short8*)&sPlo[w][lr][col];
        }
        #pragma unroll
        for (int mt = 0; mt < 4; ++mt) {
            const int d = mt * 16 + lr;
            const int swd = (d & 7) << 3;
            #pragma unroll
            for (int ks = 0; ks < 2; ++ks) {
                int col = (ks * 32 + lg * 8) ^ swd;
                short8 vh = *(const short8*)&sVhi[d][col];
                short8 vl = *(const short8*)&sVlo[d][col];
                oacc[mt] = MFMA(vh, pbh[ks], oacc[mt]);
                oacc[mt] = MFMA(vh, pbl[ks], oacc[mt]);
                oacc[mt] = MFMA(vl, pbh[ks], oacc[mt]);
            }
        }
    }

    #pragma unroll
    for (int mt = 0; mt < 4; ++mt) {
        float4 o = make_float4(oacc[mt][0], oacc[mt][1], oacc[mt][2], oacc[mt][3]);
        *(float4*)(Ow + (size_t)lr * DH + mt * 16 + lg * 4) = o;
    }
}

extern "C" void kernel_launch(void* const* d_in, const int* in_sizes, int n_in,
                              void* d_out, int out_size, void* d_ws, size_t ws_size,
                              hipStream_t stream) {
    const float* Q = (const float*)d_in[0];
    const float* K = (const float*)d_in[1];
    const float* V = (const float*)d_in[2];
    const int*   M = (const int*)d_in[3];
    float* O = (float*)d_out;
    float* P = O + (size_t)NB * NH * SL * DH;   // outputs: out, p_attn

    const size_t bm_dw = (size_t)NB * SL * BMROW;           // 512 KB
    const size_t sums_f = (size_t)NB * NH * SL;             // 256 KB
    const size_t need = bm_dw * 4 + 2 * BLOB_SH * 2 + sums_f * 4;
    if (ws_size >= need) {
        unsigned* bmp = (unsigned*)d_ws;
        unsigned short* kbp = (unsigned short*)(bmp + bm_dw);
        unsigned short* vbp = kbp + BLOB_SH;
        float* sums = (float*)(vbp + BLOB_SH);
        hipLaunchKernelGGL(prep_mask, dim3(1024, 1, 1), dim3(NT, 1, 1), 0, stream, M, bmp);
        hipLaunchKernelGGL(prep_split, dim3(NKT, NH, NB), dim3(NT, 1, 1), 0, stream,
                           K, V, kbp, vbp);
        hipLaunchKernelGGL(attn_p1, dim3(SL / BQ, NH, NB), dim3(NT, 1, 1), 0, stream,
                           Q, bmp, kbp, sums);
        hipLaunchKernelGGL(attn_p2, dim3(SL / BQ, NH, NB), dim3(NT, 1, 1), 0, stream,
                           Q, bmp, kbp, vbp, sums, O, P);
    } else {
        hipLaunchKernelGGL(attn_fallback, dim3(SL / BQ, NH, NB), dim3(NT, 1, 1), 0, stream,
                           Q, K, V, M, O, P);
    }
}

// Round 15
// 142.734 us; speedup vs baseline: 1.1371x; 1.0915x over previous
//
#include <hip/hip_runtime.h>
#include <math.h>

typedef __attribute__((ext_vector_type(8))) short short8;
typedef __attribute__((ext_vector_type(4))) float f32x4;

#define NB 4
#define NH 16
#define SL 1024
#define DH 64
#define BQ 64      // q rows per block (4 waves x 16)
#define WQ 16      // q rows per wave
#define KTL 64     // k rows per tile
#define NT 256
#define NKT (SL / KTL)                  // 16 tiles

#define TILE_SH (KTL * DH)              // 4096 shorts per tile (8 KB)
#define HEAD_SH ((size_t)NKT * TILE_SH) // 65536 shorts per head
#define BLOB_SH ((size_t)NB * NH * HEAD_SH)  // 8 MB per blob
#define BMROW   (SL / 32)               // 32 dwords of mask bits per q row

#define QSCALE 0.18033688011111543f     // 0.125 * log2(e)
#define NEGB  -1.5e9f                   // masked bias; saturates f16 -> exp2 == 0

#if __has_builtin(__builtin_amdgcn_exp2f)
#define EXP2F(x) __builtin_amdgcn_exp2f(x)
#else
#define EXP2F(x) exp2f(x)
#endif

__device__ __forceinline__ unsigned short bf_rne(float x) {
    unsigned int u = __float_as_uint(x);
    u += 0x7fffu + ((u >> 16) & 1u);
    return (unsigned short)(u >> 16);
}
__device__ __forceinline__ void bf_split(float x, unsigned short& h, unsigned short& l) {
    unsigned int u = __float_as_uint(x);
    h = (unsigned short)(u >> 16);
    float r = x - __uint_as_float(u & 0xffff0000u);
    l = bf_rne(r);
}

// f16 pack/unpack for score caching
__device__ __forceinline__ unsigned pk16(float a, float b) {
    _Float16 ha = (_Float16)a, hb = (_Float16)b;
    unsigned short ua = __builtin_bit_cast(unsigned short, ha);
    unsigned short ub = __builtin_bit_cast(unsigned short, hb);
    return (unsigned)ua | ((unsigned)ub << 16);
}
__device__ __forceinline__ void upk16(unsigned u, float& a, float& b) {
    _Float16 ha = __builtin_bit_cast(_Float16, (unsigned short)(u & 0xffffu));
    _Float16 hb = __builtin_bit_cast(_Float16, (unsigned short)(u >> 16));
    a = (float)ha;
    b = (float)hb;
}

typedef const __attribute__((address_space(1))) unsigned int guint_t;
typedef __attribute__((address_space(3))) unsigned int luint_t;
__device__ __forceinline__ void gload_lds16(const void* g, void* l) {
    __builtin_amdgcn_global_load_lds((guint_t*)g, (luint_t*)l, 16, 0, 0);
}

#define MFMA(a, b, c) __builtin_amdgcn_mfma_f32_16x16x32_bf16(a, b, c, 0, 0, 0)

#define WAITVM(N) do { asm volatile("s_waitcnt vmcnt(" #N ")" ::: "memory"); \
                       __builtin_amdgcn_sched_barrier(0); } while (0)
#define BAR() do { __builtin_amdgcn_sched_barrier(0); __builtin_amdgcn_s_barrier(); \
                   __builtin_amdgcn_sched_barrier(0); } while (0)
#define SCHED_FENCE() __builtin_amdgcn_sched_barrier(0)

// ============================================================================
// prep_mask: pack int mask [B,1,L,L] -> bitmask [B][L][L/32] via ballot
// ============================================================================
__global__ __launch_bounds__(NT, 4) void prep_mask(
    const int* __restrict__ M, unsigned* __restrict__ bm)
{
    const size_t total = (size_t)NB * SL * SL;
    const int l = threadIdx.x & 63;
    for (size_t i = (size_t)blockIdx.x * NT + threadIdx.x; i < total;
         i += (size_t)gridDim.x * NT) {
        int v = M[i];
        unsigned long long b = __ballot(v != 0);
        if (l == 0)       bm[i >> 5] = (unsigned)b;
        else if (l == 32) bm[i >> 5] = (unsigned)(b >> 32);
    }
}

// ============================================================================
// prep_split: pure-bf16 (RNE) blobs, LDS-linear swizzled (KTL=64):
//   K tile: [kr 0..63][d ^ ((kr&7)<<3)]   (row = 64 shorts)
//   V tile: [d 0..63][k ^ ((d&7)<<3)]     (row = 64 shorts)
// ============================================================================
__global__ __launch_bounds__(NT, 2) void prep_split(
    const float* __restrict__ K, const float* __restrict__ V,
    unsigned short* __restrict__ kb, unsigned short* __restrict__ vb)
{
    __shared__ float sVs[KTL][DH + 4];

    const int t = threadIdx.x;
    const int kt = blockIdx.x, h = blockIdx.y, b = blockIdx.z;
    const size_t goff = (size_t)(b * NH + h) * SL * DH + (size_t)kt * KTL * DH;
    const size_t tks = (size_t)(b * NH + h) * HEAD_SH + (size_t)kt * TILE_SH;

    #pragma unroll
    for (int u = 0; u < 2; ++u) {
        int idx = u * NT + t;
        int kr = idx >> 3, c8 = idx & 7;
        const float* src = K + goff + kr * DH + c8 * 8;
        float4 a = *(const float4*)src;
        float4 bb = *(const float4*)(src + 4);
        float vals[8] = {a.x, a.y, a.z, a.w, bb.x, bb.y, bb.z, bb.w};
        unsigned int pk[4];
        #pragma unroll
        for (int j = 0; j < 4; ++j)
            pk[j] = (unsigned int)bf_rne(vals[2 * j]) |
                    ((unsigned int)bf_rne(vals[2 * j + 1]) << 16);
        int dsw = (c8 * 8) ^ ((kr & 7) << 3);
        *(uint4*)&kb[tks + kr * DH + dsw] = make_uint4(pk[0], pk[1], pk[2], pk[3]);
    }

    #pragma unroll
    for (int u = 0; u < 4; ++u) {
        int i = u * NT + t;
        float4 v = *(const float4*)(V + goff + (size_t)i * 4);
        *(float4*)&sVs[i >> 4][(i & 15) * 4] = v;
    }
    __syncthreads();
    #pragma unroll
    for (int u = 0; u < 2; ++u) {
        int idx = u * NT + t;
        int d = idx & 63, k8 = idx >> 6;
        float vals[8];
        #pragma unroll
        for (int j = 0; j < 8; ++j) vals[j] = sVs[k8 * 8 + j][d];
        unsigned int pk[4];
        #pragma unroll
        for (int j = 0; j < 4; ++j)
            pk[j] = (unsigned int)bf_rne(vals[2 * j]) |
                    ((unsigned int)bf_rne(vals[2 * j + 1]) << 16);
        int ksw = (k8 * 8) ^ ((d & 7) << 3);
        *(uint4*)&vb[tks + d * KTL + ksw] = make_uint4(pk[0], pk[1], pk[2], pk[3]);
    }
}

// ============================================================================
// Single-pass attention: QK computed ONCE, scores cached as f16 pairs in
// 128 VGPRs; phase 1 = QK + sum, phase 2 = unpack + P + PV (V reuses the
// K staging LDS). Pure-bf16 MFMA, DMA staging, store-slack vmcnt. LDS 24KB.
// ============================================================================
__global__ __launch_bounds__(NT, 2) void attn_one(
    const float* __restrict__ Q, const unsigned* __restrict__ bm,
    const unsigned short* __restrict__ kb, const unsigned short* __restrict__ vb,
    float* __restrict__ O, float* __restrict__ P)
{
    __shared__ unsigned short sS[2][TILE_SH];   // 16 KB (K staging, then V)
    __shared__ unsigned short sPh[4][WQ][KTL];  // 8 KB

    const int t = threadIdx.x;
    const int l = t & 63;
    const int w = __builtin_amdgcn_readfirstlane(t >> 6);
    const int lg = l >> 4, lr = l & 15;

    const int flat = blockIdx.x + (blockIdx.y << 4) + (blockIdx.z << 8);
    const int nid = (flat & 7) * 128 + (flat >> 3);
    const int qt = nid & 15;
    const int hh_ = (nid >> 4) & 15;
    const int b = nid >> 8;
    const int qb = qt * BQ + w * WQ;

    const size_t hoff = (size_t)(b * NH + hh_) * SL * DH;
    const size_t headsh = (size_t)(b * NH + hh_) * HEAD_SH;
    const unsigned short* kbh = kb + headsh;
    const unsigned short* vbh = vb + headsh;
    const unsigned* bmRow = bm + ((size_t)b * SL + qb + lr) * BMROW;
    float* Pw = P + ((size_t)(b * NH + hh_) * SL + qb) * SL;
    float* Ow = O + hoff + (size_t)qb * DH;

    short8 qf[2];
    {
        const float* src0 = Q + hoff + (size_t)(qb + lr) * DH + lg * 8;
        #pragma unroll
        for (int ds = 0; ds < 2; ++ds) {
            const float* src = src0 + ds * 32;
            float4 a = *(const float4*)src;
            float4 bb = *(const float4*)(src + 4);
            float vals[8] = {a.x, a.y, a.z, a.w, bb.x, bb.y, bb.z, bb.w};
            #pragma unroll
            for (int j = 0; j < 8; ++j)
                qf[ds][j] = (short)bf_rne(vals[j] * QSCALE);
        }
    }

    auto stage = [&](unsigned short* lds, const unsigned short* gt) {
        #pragma unroll
        for (int u = 0; u < 2; ++u) {
            const int c = w * 2 + u;       // 8 x 1KB chunks
            gload_lds16((const char*)gt + c * 1024 + l * 16, (char*)lds + c * 1024);
        }
    };

    const f32x4 zero = {0.f, 0.f, 0.f, 0.f};
    unsigned su[NKT][8];                 // cached masked scores, f16 pairs
    float psum = 0.f;
    uint2 bmv, bmn;

    // ================= Phase 1: QK once, cache scores, row sums ==========
    stage(sS[0], kbh);
    bmv = *(const uint2*)&bmRow[0];

    #pragma unroll
    for (int kt = 0; kt < NKT; ++kt) {
        WAITVM(0);
        BAR();
        if (kt + 1 < NKT) {
            stage(sS[(kt + 1) & 1], kbh + (size_t)(kt + 1) * TILE_SH);
            bmn = *(const uint2*)&bmRow[2 * (kt + 1)];
        }
        SCHED_FENCE();

        f32x4 acc[4];
        #pragma unroll
        for (int st = 0; st < 4; ++st) {
            const int krow = st * 16 + lr;
            const int sw = (krow & 7) << 3;
            short8 a0 = *(const short8*)&sS[kt & 1][krow * DH + ((lg * 8) ^ sw)];
            short8 a1 = *(const short8*)&sS[kt & 1][krow * DH + ((32 + lg * 8) ^ sw)];
            f32x4 c = MFMA(a0, qf[0], zero);
            acc[st] = MFMA(a1, qf[1], c);
        }

        float ts = 0.f;
        #pragma unroll
        for (int st = 0; st < 4; ++st) {
            const unsigned bmd = (st & 2) ? bmv.y : bmv.x;
            float s[4];
            #pragma unroll
            for (int j = 0; j < 4; ++j) {
                unsigned bit = (bmd >> ((st & 1) * 16 + lg * 4 + j)) & 1u;
                s[j] = acc[st][j] + (bit ? 0.f : NEGB);
                ts += EXP2F(s[j]);
            }
            su[kt][st * 2 + 0] = pk16(s[0], s[1]);
            su[kt][st * 2 + 1] = pk16(s[2], s[3]);
        }
        psum += ts;
        bmv = bmn;
    }

    float sum = psum;
    sum += __shfl_xor(sum, 16);
    sum += __shfl_xor(sum, 32);
    sum = fmaxf(sum, 1e-35f);
    const float m2 = __log2f(sum);

    // ================= Phase 2: P + PV (V reuses sS) =====================
    WAITVM(0);
    BAR();                                // all phase-1 reads of sS done
    f32x4 oacc[4];
    #pragma unroll
    for (int mt = 0; mt < 4; ++mt) oacc[mt] = zero;

    stage(sS[0], vbh);

    #pragma unroll
    for (int kt = 0; kt < NKT; ++kt) {
        const int k0 = kt * KTL;
        // top queue (kt>=1): stage_kt(2) issued before stores_{kt-1}(4)
        if (kt == 0) { WAITVM(0); } else { WAITVM(4); }
        BAR();
        if (kt + 1 < NKT)
            stage(sS[(kt + 1) & 1], vbh + (size_t)(kt + 1) * TILE_SH);
        SCHED_FENCE();

        #pragma unroll
        for (int st = 0; st < 4; ++st) {
            float s[4];
            upk16(su[kt][st * 2 + 0], s[0], s[1]);
            upk16(su[kt][st * 2 + 1], s[2], s[3]);
            float p[4];
            #pragma unroll
            for (int j = 0; j < 4; ++j) p[j] = EXP2F(s[j] - m2);
            f32x4 pv4 = {p[0], p[1], p[2], p[3]};
            __builtin_nontemporal_store(
                pv4, (f32x4*)(Pw + (size_t)lr * SL + (k0 + st * 16 + lg * 4)));
            int col = (st * 16 + lg * 4) ^ ((lr & 7) << 3);
            uint2 uh;
            uh.x = (unsigned int)bf_rne(p[0]) | ((unsigned int)bf_rne(p[1]) << 16);
            uh.y = (unsigned int)bf_rne(p[2]) | ((unsigned int)bf_rne(p[3]) << 16);
            *(uint2*)&sPh[w][lr][col] = uh;
        }

        short8 pb0 = *(const short8*)&sPh[w][lr][(lg * 8) ^ ((lr & 7) << 3)];
        short8 pb1 = *(const short8*)&sPh[w][lr][(32 + lg * 8) ^ ((lr & 7) << 3)];
        #pragma unroll
        for (int mt = 0; mt < 4; ++mt) {
            const int d = mt * 16 + lr;
            const int sw = (d & 7) << 3;
            short8 v0 = *(const short8*)&sS[kt & 1][d * KTL + ((lg * 8) ^ sw)];
            short8 v1 = *(const short8*)&sS[kt & 1][d * KTL + ((32 + lg * 8) ^ sw)];
            oacc[mt] = MFMA(v0, pb0, oacc[mt]);
            oacc[mt] = MFMA(v1, pb1, oacc[mt]);
        }
    }

    #pragma unroll
    for (int mt = 0; mt < 4; ++mt) {
        __builtin_nontemporal_store(
            oacc[mt], (f32x4*)(Ow + (size_t)lr * DH + mt * 16 + lg * 4));
    }
}

// ============================================================================
// Fallback (verified round-2 kernel, full split precision) if ws too small
// ============================================================================
__global__ __launch_bounds__(NT, 2) void attn_fallback(
    const float* __restrict__ Q, const float* __restrict__ K,
    const float* __restrict__ V, const int* __restrict__ M,
    float* __restrict__ O, float* __restrict__ P)
{
    __shared__ unsigned short sKhi[64][DH];
    __shared__ unsigned short sKlo[64][DH];
    __shared__ unsigned short sVhi[DH][64];
    __shared__ unsigned short sVlo[DH][64];
    __shared__ unsigned short sPhi[4][WQ][64];
    __shared__ unsigned short sPlo[4][WQ][64];

    const int t = threadIdx.x;
    const int l = t & 63;
    const int w = t >> 6;
    const int lg = l >> 4;
    const int lr = l & 15;

    const int hh_ = blockIdx.y, b = blockIdx.z;
    const int qb = blockIdx.x * BQ + w * WQ;

    const size_t hoff = (size_t)(b * NH + hh_) * SL * DH;
    const float* Kh = K + hoff;
    const float* Vh = V + hoff;
    const int*   Mw = M + ((size_t)b * SL + qb) * SL;
    float*       Pw = P + ((size_t)(b * NH + hh_) * SL + qb) * SL;
    float*       Ow = O + hoff + (size_t)qb * DH;

    short8 qhi[2], qlo[2];
    {
        const float* src0 = Q + hoff + (size_t)(qb + lr) * DH + lg * 8;
        #pragma unroll
        for (int ds = 0; ds < 2; ++ds) {
            const float* src = src0 + ds * 32;
            float4 a = *(const float4*)src;
            float4 bb = *(const float4*)(src + 4);
            float vals[8] = {a.x, a.y, a.z, a.w, bb.x, bb.y, bb.z, bb.w};
            #pragma unroll
            for (int j = 0; j < 8; ++j) {
                unsigned short hv, lv;
                bf_split(vals[j] * 0.125f, hv, lv);
                qhi[ds][j] = (short)hv;
                qlo[ds][j] = (short)lv;
            }
        }
    }

    auto stageK = [&](int k0) {
        #pragma unroll
        for (int u = 0; u < 2; ++u) {
            int idx = u * NT + t;
            int kr = idx >> 3;
            int dc = (idx & 7) * 8;
            const float* src = Kh + (size_t)(k0 + kr) * DH + dc;
            float4 a = *(const float4*)src;
            float4 bb = *(const float4*)(src + 4);
            float vals[8] = {a.x, a.y, a.z, a.w, bb.x, bb.y, bb.z, bb.w};
            unsigned int ph[4], pl[4];
            #pragma unroll
            for (int j = 0; j < 4; ++j) {
                unsigned short h0, l0, h1, l1;
                bf_split(vals[2 * j], h0, l0);
                bf_split(vals[2 * j + 1], h1, l1);
                ph[j] = (unsigned int)h0 | ((unsigned int)h1 << 16);
                pl[j] = (unsigned int)l0 | ((unsigned int)l1 << 16);
            }
            int dsw = dc ^ ((kr & 7) << 3);
            *(uint4*)&sKhi[kr][dsw] = make_uint4(ph[0], ph[1], ph[2], ph[3]);
            *(uint4*)&sKlo[kr][dsw] = make_uint4(pl[0], pl[1], pl[2], pl[3]);
        }
    };

    float m = -INFINITY, sum = 0.f;
    for (int kt = 0; kt < 16; ++kt) {
        const int k0 = kt * 64;
        __syncthreads();
        stageK(k0);
        __syncthreads();
        f32x4 acc[4];
        #pragma unroll
        for (int st = 0; st < 4; ++st) {
            const int krow = st * 16 + lr;
            const int sw = (krow & 7) << 3;
            f32x4 c = {0.f, 0.f, 0.f, 0.f};
            #pragma unroll
            for (int ds = 0; ds < 2; ++ds) {
                int dc = (ds * 32 + lg * 8) ^ sw;
                short8 ah = *(const short8*)&sKhi[krow][dc];
                short8 al = *(const short8*)&sKlo[krow][dc];
                c = MFMA(ah, qhi[ds], c);
                c = MFMA(ah, qlo[ds], c);
                c = MFMA(al, qhi[ds], c);
            }
            acc[st] = c;
        }
        float s[16];
        #pragma unroll
        for (int st = 0; st < 4; ++st) {
            const int4 mv = *(const int4*)(Mw + (size_t)lr * SL + k0 + st * 16 + lg * 4);
            s[st * 4 + 0] = mv.x ? acc[st][0] : -1e9f;
            s[st * 4 + 1] = mv.y ? acc[st][1] : -1e9f;
            s[st * 4 + 2] = mv.z ? acc[st][2] : -1e9f;
            s[st * 4 + 3] = mv.w ? acc[st][3] : -1e9f;
        }
        float tmax = s[0];
        #pragma unroll
        for (int j = 1; j < 16; ++j) tmax = fmaxf(tmax, s[j]);
        tmax = fmaxf(tmax, __shfl_xor(tmax, 16));
        tmax = fmaxf(tmax, __shfl_xor(tmax, 32));
        const float mn = fmaxf(m, tmax);
        float ts = 0.f;
        #pragma unroll
        for (int j = 0; j < 16; ++j) ts += __expf(s[j] - mn);
        ts += __shfl_xor(ts, 16);
        ts += __shfl_xor(ts, 32);
        sum = sum * __expf(m - mn) + ts;
        m = mn;
    }
    const float inv = 1.f / sum;

    f32x4 oacc[4];
    #pragma unroll
    for (int mt = 0; mt < 4; ++mt) oacc[mt] = (f32x4){0.f, 0.f, 0.f, 0.f};

    for (int kt = 0; kt < 16; ++kt) {
        const int k0 = kt * 64;
        __syncthreads();
        stageK(k0);
        {
            int d0 = (t & 15) * 4;
            int kl0 = (t >> 4) * 4;
            float4 r[4];
            #pragma unroll
            for (int i = 0; i < 4; ++i)
                r[i] = *(const float4*)(Vh + (size_t)(k0 + kl0 + i) * DH + d0);
            const float* rp = (const float*)r;
            #pragma unroll
            for (int j = 0; j < 4; ++j) {
                unsigned short hv[4], lv[4];
                #pragma unroll
                for (int i = 0; i < 4; ++i) bf_split(rp[i * 4 + j], hv[i], lv[i]);
                int d = d0 + j;
                int csw = kl0 ^ ((d & 7) << 3);
                uint2 uh, ul;
                uh.x = (unsigned int)hv[0] | ((unsigned int)hv[1] << 16);
                uh.y = (unsigned int)hv[2] | ((unsigned int)hv[3] << 16);
                ul.x = (unsigned int)lv[0] | ((unsigned int)lv[1] << 16);
                ul.y = (unsigned int)lv[2] | ((unsigned int)lv[3] << 16);
                *(uint2*)&sVhi[d][csw] = uh;
                *(uint2*)&sVlo[d][csw] = ul;
            }
        }
        __syncthreads();

        #pragma unroll
        for (int st = 0; st < 4; ++st) {
            const int krow = st * 16 + lr;
            const int sw = (krow & 7) << 3;
            f32x4 c = {0.f, 0.f, 0.f, 0.f};
            #pragma unroll
            for (int ds = 0; ds < 2; ++ds) {
                int dc = (ds * 32 + lg * 8) ^ sw;
                short8 ah = *(const short8*)&sKhi[krow][dc];
                short8 al = *(const short8*)&sKlo[krow][dc];
                c = MFMA(ah, qhi[ds], c);
                c = MFMA(ah, qlo[ds], c);
                c = MFMA(al, qhi[ds], c);
            }
            const int4 mv = *(const int4*)(Mw + (size_t)lr * SL + k0 + st * 16 + lg * 4);
            float p0 = mv.x ? __expf(c[0] - m) * inv : 0.f;
            float p1 = mv.y ? __expf(c[1] - m) * inv : 0.f;
            float p2 = mv.z ? __expf(c[2] - m) * inv : 0.f;
            float p3 = mv.w ? __expf(c[3] - m) * inv : 0.f;
            *(float4*)(Pw + (size_t)lr * SL + (k0 + st * 16 + lg * 4)) =
                make_float4(p0, p1, p2, p3);
            unsigned short hv[4], lv[4];
            bf_split(p0, hv[0], lv[0]);
            bf_split(p1, hv[1], lv[1]);
            bf_split(p2, hv[2], lv[2]);
            bf_split(p3, hv[3], lv[3]);
            int col = (st * 16 + lg * 4) ^ ((lr & 7) << 3);
            uint2 uh, ul;
            uh.x = (unsigned int)hv[0] | ((unsigned int)hv[1] << 16);
            uh.y = (unsigned int)hv[2] | ((unsigned int)hv[3] << 16);
            ul.x = (unsigned int)lv[0] | ((unsigned int)lv[1] << 16);
            ul.y = (unsigned int)lv[2] | ((unsigned int)lv[3] << 16);
            *(uint2*)&sPhi[w][lr][col] = uh;
            *(uint2*)&sPlo[w][lr][col] = ul;
        }

        short8 pbh[2], pbl[2];
        #pragma unroll
        for (int ks = 0; ks < 2; ++ks) {
            int col = (ks * 32 + lg * 8) ^ ((lr & 7) << 3);
            pbh[ks] = *(const short8*)&sPhi[w][lr][col];
            pbl[ks] = *(const short8*)&sPlo[w][lr][col];
        }
        #pragma unroll
        for (int mt = 0; mt < 4; ++mt) {
            const int d = mt * 16 + lr;
            const int swd = (d & 7) << 3;
            #pragma unroll
            for (int ks = 0; ks < 2; ++ks) {
                int col = (ks * 32 + lg * 8) ^ swd;
                short8 vh = *(const short8*)&sVhi[d][col];
                short8 vl = *(const short8*)&sVlo[d][col];
                oacc[mt] = MFMA(vh, pbh[ks], oacc[mt]);
                oacc[mt] = MFMA(vh, pbl[ks], oacc[mt]);
                oacc[mt] = MFMA(vl, pbh[ks], oacc[mt]);
            }
        }
    }

    #pragma unroll
    for (int mt = 0; mt < 4; ++mt) {
        float4 o = make_float4(oacc[mt][0], oacc[mt][1], oacc[mt][2], oacc[mt][3]);
        *(float4*)(Ow + (size_t)lr * DH + mt * 16 + lg * 4) = o;
    }
}

extern "C" void kernel_launch(void* const* d_in, const int* in_sizes, int n_in,
                              void* d_out, int out_size, void* d_ws, size_t ws_size,
                              hipStream_t stream) {
    const float* Q = (const float*)d_in[0];
    const float* K = (const float*)d_in[1];
    const float* V = (const float*)d_in[2];
    const int*   M = (const int*)d_in[3];
    float* O = (float*)d_out;
    float* P = O + (size_t)NB * NH * SL * DH;   // outputs: out, p_attn

    const size_t bm_dw = (size_t)NB * SL * BMROW;          // 512 KB
    const size_t need = bm_dw * 4 + 2 * BLOB_SH * 2;       // 512KB + 16MB
    if (ws_size >= need) {
        unsigned* bmp = (unsigned*)d_ws;
        unsigned short* kbp = (unsigned short*)(bmp + bm_dw);
        unsigned short* vbp = kbp + BLOB_SH;
        hipLaunchKernelGGL(prep_mask, dim3(1024, 1, 1), dim3(NT, 1, 1), 0, stream, M, bmp);
        hipLaunchKernelGGL(prep_split, dim3(NKT, NH, NB), dim3(NT, 1, 1), 0, stream,
                           K, V, kbp, vbp);
        hipLaunchKernelGGL(attn_one, dim3(SL / BQ, NH, NB), dim3(NT, 1, 1), 0, stream,
                           Q, bmp, kbp, vbp, O, P);
    } else {
        hipLaunchKernelGGL(attn_fallback, dim3(SL / BQ, NH, NB), dim3(NT, 1, 1), 0, stream,
                           Q, K, V, M, O, P);
    }
}

// Round 16
// 127.627 us; speedup vs baseline: 1.2717x; 1.1184x over previous
//
#include <hip/hip_runtime.h>
#include <math.h>

typedef __attribute__((ext_vector_type(8))) short short8;
typedef __attribute__((ext_vector_type(4))) float f32x4;

#define NB 4
#define NH 16
#define SL 1024
#define DH 64
#define BQ 64      // q rows per block (4 waves x 16)
#define WQ 16      // q rows per wave
#define KTL 64     // k rows per tile
#define NT 256
#define NKT (SL / KTL)                  // 16 tiles

#define TILE_SH (KTL * DH)              // 4096 shorts per tile (8 KB)
#define HEAD_SH ((size_t)NKT * TILE_SH) // 65536 shorts per head
#define BLOB_SH ((size_t)NB * NH * HEAD_SH)  // 8 MB per blob
#define BMROW   (SL / 32)               // 32 dwords of mask bits per q row

#define QSCALE 0.18033688011111543f     // 0.125 * log2(e)
#define NEGB  -1.5e9f                   // masked bias; saturates f16 -> exp2 == 0

#if __has_builtin(__builtin_amdgcn_exp2f)
#define EXP2F(x) __builtin_amdgcn_exp2f(x)
#else
#define EXP2F(x) exp2f(x)
#endif

__device__ __forceinline__ unsigned short bf_rne(float x) {
    unsigned int u = __float_as_uint(x);
    u += 0x7fffu + ((u >> 16) & 1u);
    return (unsigned short)(u >> 16);
}
__device__ __forceinline__ void bf_split(float x, unsigned short& h, unsigned short& l) {
    unsigned int u = __float_as_uint(x);
    h = (unsigned short)(u >> 16);
    float r = x - __uint_as_float(u & 0xffff0000u);
    l = bf_rne(r);
}

// f16 pack/unpack for score caching
__device__ __forceinline__ unsigned pk16(float a, float b) {
    _Float16 ha = (_Float16)a, hb = (_Float16)b;
    unsigned short ua = __builtin_bit_cast(unsigned short, ha);
    unsigned short ub = __builtin_bit_cast(unsigned short, hb);
    return (unsigned)ua | ((unsigned)ub << 16);
}
__device__ __forceinline__ void upk16(unsigned u, float& a, float& b) {
    _Float16 ha = __builtin_bit_cast(_Float16, (unsigned short)(u & 0xffffu));
    _Float16 hb = __builtin_bit_cast(_Float16, (unsigned short)(u >> 16));
    a = (float)ha;
    b = (float)hb;
}

typedef const __attribute__((address_space(1))) unsigned int guint_t;
typedef __attribute__((address_space(3))) unsigned int luint_t;
__device__ __forceinline__ void gload_lds16(const void* g, void* l) {
    __builtin_amdgcn_global_load_lds((guint_t*)g, (luint_t*)l, 16, 0, 0);
}

#define MFMA(a, b, c) __builtin_amdgcn_mfma_f32_16x16x32_bf16(a, b, c, 0, 0, 0)

#define WAITVM(N) do { asm volatile("s_waitcnt vmcnt(" #N ")" ::: "memory"); \
                       __builtin_amdgcn_sched_barrier(0); } while (0)
#define BAR() do { __builtin_amdgcn_sched_barrier(0); __builtin_amdgcn_s_barrier(); \
                   __builtin_amdgcn_sched_barrier(0); } while (0)
#define SCHED_FENCE() __builtin_amdgcn_sched_barrier(0)

// ============================================================================
// prep_mask: pack int mask [B,1,L,L] -> bitmask [B][L][L/32] via ballot
// ============================================================================
__global__ __launch_bounds__(NT, 4) void prep_mask(
    const int* __restrict__ M, unsigned* __restrict__ bm)
{
    const size_t total = (size_t)NB * SL * SL;
    const int l = threadIdx.x & 63;
    for (size_t i = (size_t)blockIdx.x * NT + threadIdx.x; i < total;
         i += (size_t)gridDim.x * NT) {
        int v = M[i];
        unsigned long long b = __ballot(v != 0);
        if (l == 0)       bm[i >> 5] = (unsigned)b;
        else if (l == 32) bm[i >> 5] = (unsigned)(b >> 32);
    }
}

// ============================================================================
// prep_split: pure-bf16 (RNE) blobs, LDS-linear swizzled (KTL=64):
//   K tile: [kr 0..63][d ^ ((kr&7)<<3)]   (row = 64 shorts)
//   V tile: [d 0..63][k ^ ((d&7)<<3)]     (row = 64 shorts)
// ============================================================================
__global__ __launch_bounds__(NT, 2) void prep_split(
    const float* __restrict__ K, const float* __restrict__ V,
    unsigned short* __restrict__ kb, unsigned short* __restrict__ vb)
{
    __shared__ float sVs[KTL][DH + 4];

    const int t = threadIdx.x;
    const int kt = blockIdx.x, h = blockIdx.y, b = blockIdx.z;
    const size_t goff = (size_t)(b * NH + h) * SL * DH + (size_t)kt * KTL * DH;
    const size_t tks = (size_t)(b * NH + h) * HEAD_SH + (size_t)kt * TILE_SH;

    #pragma unroll
    for (int u = 0; u < 2; ++u) {
        int idx = u * NT + t;
        int kr = idx >> 3, c8 = idx & 7;
        const float* src = K + goff + kr * DH + c8 * 8;
        float4 a = *(const float4*)src;
        float4 bb = *(const float4*)(src + 4);
        float vals[8] = {a.x, a.y, a.z, a.w, bb.x, bb.y, bb.z, bb.w};
        unsigned int pk[4];
        #pragma unroll
        for (int j = 0; j < 4; ++j)
            pk[j] = (unsigned int)bf_rne(vals[2 * j]) |
                    ((unsigned int)bf_rne(vals[2 * j + 1]) << 16);
        int dsw = (c8 * 8) ^ ((kr & 7) << 3);
        *(uint4*)&kb[tks + kr * DH + dsw] = make_uint4(pk[0], pk[1], pk[2], pk[3]);
    }

    #pragma unroll
    for (int u = 0; u < 4; ++u) {
        int i = u * NT + t;
        float4 v = *(const float4*)(V + goff + (size_t)i * 4);
        *(float4*)&sVs[i >> 4][(i & 15) * 4] = v;
    }
    __syncthreads();
    #pragma unroll
    for (int u = 0; u < 2; ++u) {
        int idx = u * NT + t;
        int d = idx & 63, k8 = idx >> 6;
        float vals[8];
        #pragma unroll
        for (int j = 0; j < 8; ++j) vals[j] = sVs[k8 * 8 + j][d];
        unsigned int pk[4];
        #pragma unroll
        for (int j = 0; j < 4; ++j)
            pk[j] = (unsigned int)bf_rne(vals[2 * j]) |
                    ((unsigned int)bf_rne(vals[2 * j + 1]) << 16);
        int ksw = (k8 * 8) ^ ((d & 7) << 3);
        *(uint4*)&vb[tks + d * KTL + ksw] = make_uint4(pk[0], pk[1], pk[2], pk[3]);
    }
}

// ============================================================================
// Single-pass attention: QK once (scores f16-cached in 128 VGPRs), PV with
// bf16 p, and P written via LDS transpose buffer in 1KB-contiguous wave
// stores (phase 2b) instead of per-tile 64B scatter. LDS 58.5KB, 2 blk/CU.
// ============================================================================
__global__ __launch_bounds__(NT, 2) void attn_one(
    const float* __restrict__ Q, const unsigned* __restrict__ bm,
    const unsigned short* __restrict__ kb, const unsigned short* __restrict__ vb,
    float* __restrict__ O, float* __restrict__ P)
{
    __shared__ unsigned short sS[2][TILE_SH];   // 16 KB (K staging, then V)
    __shared__ unsigned short sPh[4][WQ][KTL];  // 8 KB (PV fragment relay)
    __shared__ unsigned short sPb[BQ][264];     // 33 KB (P row-dump buffer)

    const int t = threadIdx.x;
    const int l = t & 63;
    const int w = __builtin_amdgcn_readfirstlane(t >> 6);
    const int lg = l >> 4, lr = l & 15;

    const int flat = blockIdx.x + (blockIdx.y << 4) + (blockIdx.z << 8);
    const int nid = (flat & 7) * 128 + (flat >> 3);
    const int qt = nid & 15;
    const int hh_ = (nid >> 4) & 15;
    const int b = nid >> 8;
    const int qb = qt * BQ + w * WQ;

    const size_t hoff = (size_t)(b * NH + hh_) * SL * DH;
    const size_t headsh = (size_t)(b * NH + hh_) * HEAD_SH;
    const unsigned short* kbh = kb + headsh;
    const unsigned short* vbh = vb + headsh;
    const unsigned* bmRow = bm + ((size_t)b * SL + qb + lr) * BMROW;
    float* Pblk = P + (((size_t)(b * NH + hh_) * SL) + (size_t)qt * BQ) * SL;
    float* Ow = O + hoff + (size_t)qb * DH;

    short8 qf[2];
    {
        const float* src0 = Q + hoff + (size_t)(qb + lr) * DH + lg * 8;
        #pragma unroll
        for (int ds = 0; ds < 2; ++ds) {
            const float* src = src0 + ds * 32;
            float4 a = *(const float4*)src;
            float4 bb = *(const float4*)(src + 4);
            float vals[8] = {a.x, a.y, a.z, a.w, bb.x, bb.y, bb.z, bb.w};
            #pragma unroll
            for (int j = 0; j < 8; ++j)
                qf[ds][j] = (short)bf_rne(vals[j] * QSCALE);
        }
    }

    auto stage = [&](unsigned short* lds, const unsigned short* gt) {
        #pragma unroll
        for (int u = 0; u < 2; ++u) {
            const int c = w * 2 + u;       // 8 x 1KB chunks
            gload_lds16((const char*)gt + c * 1024 + l * 16, (char*)lds + c * 1024);
        }
    };

    const f32x4 zero = {0.f, 0.f, 0.f, 0.f};
    unsigned su[NKT][8];                 // phase1: s f16 pairs; phase2a: p bf16 pairs
    float psum = 0.f;
    uint2 bmv, bmn;

    // ================= Phase 1: QK once, cache scores, row sums ==========
    stage(sS[0], kbh);
    bmv = *(const uint2*)&bmRow[0];

    #pragma unroll
    for (int kt = 0; kt < NKT; ++kt) {
        WAITVM(0);
        BAR();
        if (kt + 1 < NKT) {
            stage(sS[(kt + 1) & 1], kbh + (size_t)(kt + 1) * TILE_SH);
            bmn = *(const uint2*)&bmRow[2 * (kt + 1)];
        }
        SCHED_FENCE();

        f32x4 acc[4];
        #pragma unroll
        for (int st = 0; st < 4; ++st) {
            const int krow = st * 16 + lr;
            const int sw = (krow & 7) << 3;
            short8 a0 = *(const short8*)&sS[kt & 1][krow * DH + ((lg * 8) ^ sw)];
            short8 a1 = *(const short8*)&sS[kt & 1][krow * DH + ((32 + lg * 8) ^ sw)];
            f32x4 c = MFMA(a0, qf[0], zero);
            acc[st] = MFMA(a1, qf[1], c);
        }

        float ts = 0.f;
        #pragma unroll
        for (int st = 0; st < 4; ++st) {
            const unsigned bmd = (st & 2) ? bmv.y : bmv.x;
            float s[4];
            #pragma unroll
            for (int j = 0; j < 4; ++j) {
                unsigned bit = (bmd >> ((st & 1) * 16 + lg * 4 + j)) & 1u;
                s[j] = acc[st][j] + (bit ? 0.f : NEGB);
                ts += EXP2F(s[j]);
            }
            su[kt][st * 2 + 0] = pk16(s[0], s[1]);
            su[kt][st * 2 + 1] = pk16(s[2], s[3]);
        }
        psum += ts;
        bmv = bmn;
    }

    float sum = psum;
    sum += __shfl_xor(sum, 16);
    sum += __shfl_xor(sum, 32);
    sum = fmaxf(sum, 1e-35f);
    const float m2 = __log2f(sum);

    // ================= Phase 2a: p + PV (V reuses sS); su := p (bf16) ====
    WAITVM(0);
    BAR();                                // all phase-1 reads of sS done
    f32x4 oacc[4];
    #pragma unroll
    for (int mt = 0; mt < 4; ++mt) oacc[mt] = zero;

    stage(sS[0], vbh);

    #pragma unroll
    for (int kt = 0; kt < NKT; ++kt) {
        WAITVM(0);
        BAR();
        if (kt + 1 < NKT)
            stage(sS[(kt + 1) & 1], vbh + (size_t)(kt + 1) * TILE_SH);
        SCHED_FENCE();

        #pragma unroll
        for (int st = 0; st < 4; ++st) {
            float s[4];
            upk16(su[kt][st * 2 + 0], s[0], s[1]);
            upk16(su[kt][st * 2 + 1], s[2], s[3]);
            float p[4];
            #pragma unroll
            for (int j = 0; j < 4; ++j) p[j] = EXP2F(s[j] - m2);
            unsigned u0 = (unsigned)bf_rne(p[0]) | ((unsigned)bf_rne(p[1]) << 16);
            unsigned u1 = (unsigned)bf_rne(p[2]) | ((unsigned)bf_rne(p[3]) << 16);
            su[kt][st * 2 + 0] = u0;       // cache p for phase 2b dump
            su[kt][st * 2 + 1] = u1;
            int col = (st * 16 + lg * 4) ^ ((lr & 7) << 3);
            *(uint2*)&sPh[w][lr][col] = make_uint2(u0, u1);
        }

        short8 pb0 = *(const short8*)&sPh[w][lr][(lg * 8) ^ ((lr & 7) << 3)];
        short8 pb1 = *(const short8*)&sPh[w][lr][(32 + lg * 8) ^ ((lr & 7) << 3)];
        #pragma unroll
        for (int mt = 0; mt < 4; ++mt) {
            const int d = mt * 16 + lr;
            const int sw = (d & 7) << 3;
            short8 v0 = *(const short8*)&sS[kt & 1][d * KTL + ((lg * 8) ^ sw)];
            short8 v1 = *(const short8*)&sS[kt & 1][d * KTL + ((32 + lg * 8) ^ sw)];
            oacc[mt] = MFMA(v0, pb0, oacc[mt]);
            oacc[mt] = MFMA(v1, pb1, oacc[mt]);
        }
    }

    // O stores (frees oacc before the dump phase)
    #pragma unroll
    for (int mt = 0; mt < 4; ++mt) {
        __builtin_nontemporal_store(
            oacc[mt], (f32x4*)(Ow + (size_t)lr * DH + mt * 16 + lg * 4));
    }

    // ================= Phase 2b: P dump, 1KB-contiguous wave stores ======
    BAR();                                // phase-2a sPh/sS traffic settled
    #pragma unroll
    for (int g = 0; g < 4; ++g) {
        #pragma unroll
        for (int kk = 0; kk < 4; ++kk) {
            const int kt = g * 4 + kk;
            #pragma unroll
            for (int st = 0; st < 4; ++st) {
                const int c = kk * 64 + st * 16 + lg * 4;
                *(uint2*)&sPb[w * WQ + lr][c] =
                    make_uint2(su[kt][st * 2 + 0], su[kt][st * 2 + 1]);
            }
        }
        BAR();                            // all waves' group-g p in sPb
        #pragma unroll
        for (int it = 0; it < 16; ++it) {
            const int row = it * 4 + w;   // each wave-store = one full 1KB row span
            const uint2 u = *(const uint2*)&sPb[row][l * 4];
            f32x4 pv;
            pv[0] = __uint_as_float(u.x << 16);
            pv[1] = __uint_as_float(u.x & 0xffff0000u);
            pv[2] = __uint_as_float(u.y << 16);
            pv[3] = __uint_as_float(u.y & 0xffff0000u);
            __builtin_nontemporal_store(
                pv, (f32x4*)(Pblk + (size_t)row * SL + g * 256 + l * 4));
        }
        BAR();                            // dump reads done before buffer reuse
    }
}

// ============================================================================
// Fallback (verified round-2 kernel, full split precision) if ws too small
// ============================================================================
__global__ __launch_bounds__(NT, 2) void attn_fallback(
    const float* __restrict__ Q, const float* __restrict__ K,
    const float* __restrict__ V, const int* __restrict__ M,
    float* __restrict__ O, float* __restrict__ P)
{
    __shared__ unsigned short sKhi[64][DH];
    __shared__ unsigned short sKlo[64][DH];
    __shared__ unsigned short sVhi[DH][64];
    __shared__ unsigned short sVlo[DH][64];
    __shared__ unsigned short sPhi[4][WQ][64];
    __shared__ unsigned short sPlo[4][WQ][64];

    const int t = threadIdx.x;
    const int l = t & 63;
    const int w = t >> 6;
    const int lg = l >> 4;
    const int lr = l & 15;

    const int hh_ = blockIdx.y, b = blockIdx.z;
    const int qb = blockIdx.x * BQ + w * WQ;

    const size_t hoff = (size_t)(b * NH + hh_) * SL * DH;
    const float* Kh = K + hoff;
    const float* Vh = V + hoff;
    const int*   Mw = M + ((size_t)b * SL + qb) * SL;
    float*       Pw = P + ((size_t)(b * NH + hh_) * SL + qb) * SL;
    float*       Ow = O + hoff + (size_t)qb * DH;

    short8 qhi[2], qlo[2];
    {
        const float* src0 = Q + hoff + (size_t)(qb + lr) * DH + lg * 8;
        #pragma unroll
        for (int ds = 0; ds < 2; ++ds) {
            const float* src = src0 + ds * 32;
            float4 a = *(const float4*)src;
            float4 bb = *(const float4*)(src + 4);
            float vals[8] = {a.x, a.y, a.z, a.w, bb.x, bb.y, bb.z, bb.w};
            #pragma unroll
            for (int j = 0; j < 8; ++j) {
                unsigned short hv, lv;
                bf_split(vals[j] * 0.125f, hv, lv);
                qhi[ds][j] = (short)hv;
                qlo[ds][j] = (short)lv;
            }
        }
    }

    auto stageK = [&](int k0) {
        #pragma unroll
        for (int u = 0; u < 2; ++u) {
            int idx = u * NT + t;
            int kr = idx >> 3;
            int dc = (idx & 7) * 8;
            const float* src = Kh + (size_t)(k0 + kr) * DH + dc;
            float4 a = *(const float4*)src;
            float4 bb = *(const float4*)(src + 4);
            float vals[8] = {a.x, a.y, a.z, a.w, bb.x, bb.y, bb.z, bb.w};
            unsigned int ph[4], pl[4];
            #pragma unroll
            for (int j = 0; j < 4; ++j) {
                unsigned short h0, l0, h1, l1;
                bf_split(vals[2 * j], h0, l0);
                bf_split(vals[2 * j + 1], h1, l1);
                ph[j] = (unsigned int)h0 | ((unsigned int)h1 << 16);
                pl[j] = (unsigned int)l0 | ((unsigned int)l1 << 16);
            }
            int dsw = dc ^ ((kr & 7) << 3);
            *(uint4*)&sKhi[kr][dsw] = make_uint4(ph[0], ph[1], ph[2], ph[3]);
            *(uint4*)&sKlo[kr][dsw] = make_uint4(pl[0], pl[1], pl[2], pl[3]);
        }
    };

    float m = -INFINITY, sum = 0.f;
    for (int kt = 0; kt < 16; ++kt) {
        const int k0 = kt * 64;
        __syncthreads();
        stageK(k0);
        __syncthreads();
        f32x4 acc[4];
        #pragma unroll
        for (int st = 0; st < 4; ++st) {
            const int krow = st * 16 + lr;
            const int sw = (krow & 7) << 3;
            f32x4 c = {0.f, 0.f, 0.f, 0.f};
            #pragma unroll
            for (int ds = 0; ds < 2; ++ds) {
                int dc = (ds * 32 + lg * 8) ^ sw;
                short8 ah = *(const short8*)&sKhi[krow][dc];
                short8 al = *(const short8*)&sKlo[krow][dc];
                c = MFMA(ah, qhi[ds], c);
                c = MFMA(ah, qlo[ds], c);
                c = MFMA(al, qhi[ds], c);
            }
            acc[st] = c;
        }
        float s[16];
        #pragma unroll
        for (int st = 0; st < 4; ++st) {
            const int4 mv = *(const int4*)(Mw + (size_t)lr * SL + k0 + st * 16 + lg * 4);
            s[st * 4 + 0] = mv.x ? acc[st][0] : -1e9f;
            s[st * 4 + 1] = mv.y ? acc[st][1] : -1e9f;
            s[st * 4 + 2] = mv.z ? acc[st][2] : -1e9f;
            s[st * 4 + 3] = mv.w ? acc[st][3] : -1e9f;
        }
        float tmax = s[0];
        #pragma unroll
        for (int j = 1; j < 16; ++j) tmax = fmaxf(tmax, s[j]);
        tmax = fmaxf(tmax, __shfl_xor(tmax, 16));
        tmax = fmaxf(tmax, __shfl_xor(tmax, 32));
        const float mn = fmaxf(m, tmax);
        float ts = 0.f;
        #pragma unroll
        for (int j = 0; j < 16; ++j) ts += __expf(s[j] - mn);
        ts += __shfl_xor(ts, 16);
        ts += __shfl_xor(ts, 32);
        sum = sum * __expf(m - mn) + ts;
        m = mn;
    }
    const float inv = 1.f / sum;

    f32x4 oacc[4];
    #pragma unroll
    for (int mt = 0; mt < 4; ++mt) oacc[mt] = (f32x4){0.f, 0.f, 0.f, 0.f};

    for (int kt = 0; kt < 16; ++kt) {
        const int k0 = kt * 64;
        __syncthreads();
        stageK(k0);
        {
            int d0 = (t & 15) * 4;
            int kl0 = (t >> 4) * 4;
            float4 r[4];
            #pragma unroll
            for (int i = 0; i < 4; ++i)
                r[i] = *(const float4*)(Vh + (size_t)(k0 + kl0 + i) * DH + d0);
            const float* rp = (const float*)r;
            #pragma unroll
            for (int j = 0; j < 4; ++j) {
                unsigned short hv[4], lv[4];
                #pragma unroll
                for (int i = 0; i < 4; ++i) bf_split(rp[i * 4 + j], hv[i], lv[i]);
                int d = d0 + j;
                int csw = kl0 ^ ((d & 7) << 3);
                uint2 uh, ul;
                uh.x = (unsigned int)hv[0] | ((unsigned int)hv[1] << 16);
                uh.y = (unsigned int)hv[2] | ((unsigned int)hv[3] << 16);
                ul.x = (unsigned int)lv[0] | ((unsigned int)lv[1] << 16);
                ul.y = (unsigned int)lv[2] | ((unsigned int)lv[3] << 16);
                *(uint2*)&sVhi[d][csw] = uh;
                *(uint2*)&sVlo[d][csw] = ul;
            }
        }
        __syncthreads();

        #pragma unroll
        for (int st = 0; st < 4; ++st) {
            const int krow = st * 16 + lr;
            const int sw = (krow & 7) << 3;
            f32x4 c = {0.f, 0.f, 0.f, 0.f};
            #pragma unroll
            for (int ds = 0; ds < 2; ++ds) {
                int dc = (ds * 32 + lg * 8) ^ sw;
                short8 ah = *(const short8*)&sKhi[krow][dc];
                short8 al = *(const short8*)&sKlo[krow][dc];
                c = MFMA(ah, qhi[ds], c);
                c = MFMA(ah, qlo[ds], c);
                c = MFMA(al, qhi[ds], c);
            }
            const int4 mv = *(const int4*)(Mw + (size_t)lr * SL + k0 + st * 16 + lg * 4);
            float p0 = mv.x ? __expf(c[0] - m) * inv : 0.f;
            float p1 = mv.y ? __expf(c[1] - m) * inv : 0.f;
            float p2 = mv.z ? __expf(c[2] - m) * inv : 0.f;
            float p3 = mv.w ? __expf(c[3] - m) * inv : 0.f;
            *(float4*)(Pw + (size_t)lr * SL + (k0 + st * 16 + lg * 4)) =
                make_float4(p0, p1, p2, p3);
            unsigned short hv[4], lv[4];
            bf_split(p0, hv[0], lv[0]);
            bf_split(p1, hv[1], lv[1]);
            bf_split(p2, hv[2], lv[2]);
            bf_split(p3, hv[3], lv[3]);
            int col = (st * 16 + lg * 4) ^ ((lr & 7) << 3);
            uint2 uh, ul;
            uh.x = (unsigned int)hv[0] | ((unsigned int)hv[1] << 16);
            uh.y = (unsigned int)hv[2] | ((unsigned int)hv[3] << 16);
            ul.x = (unsigned int)lv[0] | ((unsigned int)lv[1] << 16);
            ul.y = (unsigned int)lv[2] | ((unsigned int)lv[3] << 16);
            *(uint2*)&sPhi[w][lr][col] = uh;
            *(uint2*)&sPlo[w][lr][col] = ul;
        }

        short8 pbh[2], pbl[2];
        #pragma unroll
        for (int ks = 0; ks < 2; ++ks) {
            int col = (ks * 32 + lg * 8) ^ ((lr & 7) << 3);
            pbh[ks] = *(const short8*)&sPhi[w][lr][col];
            pbl[ks] = *(const short8*)&sPlo[w][lr][col];
        }
        #pragma unroll
        for (int mt = 0; mt < 4; ++mt) {
            const int d = mt * 16 + lr;
            const int swd = (d & 7) << 3;
            #pragma unroll
            for (int ks = 0; ks < 2; ++ks) {
                int col = (ks * 32 + lg * 8) ^ swd;
                short8 vh = *(const short8*)&sVhi[d][col];
                short8 vl = *(const short8*)&sVlo[d][col];
                oacc[mt] = MFMA(vh, pbh[ks], oacc[mt]);
                oacc[mt] = MFMA(vh, pbl[ks], oacc[mt]);
                oacc[mt] = MFMA(vl, pbh[ks], oacc[mt]);
            }
        }
    }

    #pragma unroll
    for (int mt = 0; mt < 4; ++mt) {
        float4 o = make_float4(oacc[mt][0], oacc[mt][1], oacc[mt][2], oacc[mt][3]);
        *(float4*)(Ow + (size_t)lr * DH + mt * 16 + lg * 4) = o;
    }
}

extern "C" void kernel_launch(void* const* d_in, const int* in_sizes, int n_in,
                              void* d_out, int out_size, void* d_ws, size_t ws_size,
                              hipStream_t stream) {
    const float* Q = (const float*)d_in[0];
    const float* K = (const float*)d_in[1];
    const float* V = (const float*)d_in[2];
    const int*   M = (const int*)d_in[3];
    float* O = (float*)d_out;
    float* P = O + (size_t)NB * NH * SL * DH;   // outputs: out, p_attn

    const size_t bm_dw = (size_t)NB * SL * BMROW;          // 512 KB
    const size_t need = bm_dw * 4 + 2 * BLOB_SH * 2;       // 512KB + 16MB
    if (ws_size >= need) {
        unsigned* bmp = (unsigned*)d_ws;
        unsigned short* kbp = (unsigned short*)(bmp + bm_dw);
        unsigned short* vbp = kbp + BLOB_SH;
        hipLaunchKernelGGL(prep_mask, dim3(1024, 1, 1), dim3(NT, 1, 1), 0, stream, M, bmp);
        hipLaunchKernelGGL(prep_split, dim3(NKT, NH, NB), dim3(NT, 1, 1), 0, stream,
                           K, V, kbp, vbp);
        hipLaunchKernelGGL(attn_one, dim3(SL / BQ, NH, NB), dim3(NT, 1, 1), 0, stream,
                           Q, bmp, kbp, vbp, O, P);
    } else {
        hipLaunchKernelGGL(attn_fallback, dim3(SL / BQ, NH, NB), dim3(NT, 1, 1), 0, stream,
                           Q, K, V, M, O, P);
    }
}